// Round 3
// baseline (459.888 us; speedup 1.0000x reference)
//
#include <hip/hip_runtime.h>
#include <math.h>

// ToyModel: B=4, S=2048, E=256, H=512, VOCAB=50257.
// Inputs/output are FLOAT32 (per reference dtypes); token_ids int32.
// posneg(x) == x identically -> dropped.
//
// Pipeline (intermediates stored bf16, MFMA bf16 compute, f32 accumulate):
//   act = gelu_exact(emb[tok] @ W1 + b1)   [8192,512] bf16 -> stored in d_out (dead before final write)
//   q/k/v = act @ W{q,k,v} + b             [8192,512] bf16 -> ws
//   per batch b (sc reused):
//     sc  = (q_b @ k_b^T)/sqrt(512)        [2048,2048] bf16
//     p   = softmax(sc)                     in place
//     out_b = p @ v_b                      [2048,512] f32 -> d_out
//
// ws: q@0 | k@8MiB | v@16MiB | sc@24MiB == 32 MiB total.

typedef unsigned short u16;
typedef u16   u16x8 __attribute__((ext_vector_type(8)));
typedef short s16x8 __attribute__((ext_vector_type(8)));   // bf16 frag for MFMA
typedef float f32x4 __attribute__((ext_vector_type(4)));
typedef float f32x8 __attribute__((ext_vector_type(8)));

static __device__ __forceinline__ float bf2f(u16 h) {
    unsigned u = ((unsigned)h) << 16;
    return __builtin_bit_cast(float, u);
}
static __device__ __forceinline__ u16 f2bf(float f) {
    unsigned u = __builtin_bit_cast(unsigned, f);
    u = (u + 0x7fffu + ((u >> 16) & 1u)) >> 16;   // RNE
    return (u16)u;
}

// EPI: 0 = scale only, 1 = +bias, 2 = +bias then exact GELU
// BT : true  -> B global layout [K][N] (transpose into LDS Bs[n][k])
//      false -> B global layout [N][K] (k-contiguous rows, direct stage)
// AF32/BF32: global A/B are float32 (convert to bf16 while staging). CF32: store f32.
template <int EPI, bool BT, bool AF32, bool BF32, bool CF32>
__launch_bounds__(256)
__global__ void gemm_k(const void* __restrict__ Ap, const void* __restrict__ Bp,
                       const float* __restrict__ bias, void* __restrict__ Cp,
                       const int* __restrict__ gather,
                       int M, int N, int K, int lda, int ldb, int ldc, float scale)
{
    __shared__ u16 As[64 * 40];   // [m][k], row stride 40 (pad: only 2-way bank alias)
    __shared__ u16 Bs[64 * 40];   // [n][k]

    const int m0 = blockIdx.y * 64;
    const int n0 = blockIdx.x * 64;
    const int t    = threadIdx.x;
    const int wid  = t >> 6;
    const int lane = t & 63;
    const int quad = lane >> 4;
    const int l16  = lane & 15;

    f32x4 acc[4] = {};

    // A staging indices: thread -> (row 0..63, 8-col group)
    const int ar = t >> 2;
    const int ac = (t & 3) * 8;
    long arowbase;
    {
        int gr = m0 + ar;
        int arow = gather ? gather[gr] : gr;
        arowbase = (long)arow * lda + ac;
    }
    // B staging indices
    const int bk = t >> 3;          // BT=true : k row 0..31
    const int bn = (t & 7) * 8;     //           8-col group along n
    const int br = t >> 2;          // BT=false: n row 0..63
    const int bc = (t & 3) * 8;     //           8-col group along k

    for (int k0 = 0; k0 < K; k0 += 32) {
        u16x8 av;
        if (AF32) {
            f32x8 af = *(const f32x8*)((const float*)Ap + arowbase + k0);
#pragma unroll
            for (int i = 0; i < 8; ++i) av[i] = f2bf(af[i]);
        } else {
            av = *(const u16x8*)((const u16*)Ap + arowbase + k0);
        }
        *(u16x8*)&As[ar * 40 + ac] = av;

        if (BT) {
            u16x8 bv;
            if (BF32) {
                f32x8 bf = *(const f32x8*)((const float*)Bp + (long)(k0 + bk) * ldb + n0 + bn);
#pragma unroll
                for (int i = 0; i < 8; ++i) bv[i] = f2bf(bf[i]);
            } else {
                bv = *(const u16x8*)((const u16*)Bp + (long)(k0 + bk) * ldb + n0 + bn);
            }
#pragma unroll
            for (int i = 0; i < 8; ++i) Bs[(bn + i) * 40 + bk] = bv[i];
        } else {
            u16x8 bv;
            if (BF32) {
                f32x8 bf = *(const f32x8*)((const float*)Bp + (long)(n0 + br) * ldb + k0 + bc);
#pragma unroll
                for (int i = 0; i < 8; ++i) bv[i] = f2bf(bf[i]);
            } else {
                bv = *(const u16x8*)((const u16*)Bp + (long)(n0 + br) * ldb + k0 + bc);
            }
            *(u16x8*)&Bs[br * 40 + bc] = bv;
        }
        __syncthreads();

        s16x8 a = *(const s16x8*)&As[(wid * 16 + l16) * 40 + quad * 8];
#pragma unroll
        for (int nt = 0; nt < 4; ++nt) {
            s16x8 b = *(const s16x8*)&Bs[(nt * 16 + l16) * 40 + quad * 8];
            acc[nt] = __builtin_amdgcn_mfma_f32_16x16x32_bf16(a, b, acc[nt], 0, 0, 0);
        }
        __syncthreads();
    }

#pragma unroll
    for (int nt = 0; nt < 4; ++nt) {
        const int col = n0 + nt * 16 + l16;
        const float bval = (EPI >= 1) ? bias[col] : 0.0f;
#pragma unroll
        for (int r = 0; r < 4; ++r) {
            const int row = m0 + wid * 16 + quad * 4 + r;
            float x = acc[nt][r] * scale + bval;
            if (EPI == 2) x = 0.5f * x * (1.0f + erff(x * 0.70710678118654752f));
            if (CF32) ((float*)Cp)[(long)row * ldc + col] = x;
            else      ((u16*)Cp)[(long)row * ldc + col] = f2bf(x);
        }
    }
}

// One block per score row, softmax in place over S=2048 bf16 columns.
__launch_bounds__(256)
__global__ void softmax_k(u16* __restrict__ sc, int S)
{
    const long base = (long)blockIdx.x * S;
    const int t = threadIdx.x;
    const int wid = t >> 6, lane = t & 63;
    __shared__ float redm[4];
    __shared__ float reds[4];

    float v[8];
    float mx = -1e30f;
#pragma unroll
    for (int i = 0; i < 8; ++i) {
        v[i] = bf2f(sc[base + i * 256 + t]);
        mx = fmaxf(mx, v[i]);
    }
#pragma unroll
    for (int off = 32; off; off >>= 1) mx = fmaxf(mx, __shfl_xor(mx, off, 64));
    if (lane == 0) redm[wid] = mx;
    __syncthreads();
    const float bm = fmaxf(fmaxf(redm[0], redm[1]), fmaxf(redm[2], redm[3]));

    float s = 0.0f;
#pragma unroll
    for (int i = 0; i < 8; ++i) { v[i] = expf(v[i] - bm); s += v[i]; }
#pragma unroll
    for (int off = 32; off; off >>= 1) s += __shfl_xor(s, off, 64);
    if (lane == 0) reds[wid] = s;
    __syncthreads();
    const float inv = 1.0f / (reds[0] + reds[1] + reds[2] + reds[3]);

#pragma unroll
    for (int i = 0; i < 8; ++i) sc[base + i * 256 + t] = f2bf(v[i] * inv);
}

extern "C" void kernel_launch(void* const* d_in, const int* in_sizes, int n_in,
                              void* d_out, int out_size, void* d_ws, size_t ws_size,
                              hipStream_t stream)
{
    const int*   tok = (const int*)d_in[0];
    const float* emb = (const float*)d_in[1];
    const float* W1  = (const float*)d_in[2];
    const float* b1  = (const float*)d_in[3];
    const float* Wq  = (const float*)d_in[4];
    const float* bq  = (const float*)d_in[5];
    const float* Wk  = (const float*)d_in[6];
    const float* bk  = (const float*)d_in[7];
    const float* Wv  = (const float*)d_in[8];
    const float* bv  = (const float*)d_in[9];
    float* out = (float*)d_out;

    char* ws = (char*)d_ws;
    u16* q  = (u16*)(ws);
    u16* k  = (u16*)(ws + (8l  << 20));
    u16* v  = (u16*)(ws + (16l << 20));
    u16* sc = (u16*)(ws + (24l << 20));   // 8 MiB, reused per batch
    u16* act = (u16*)d_out;               // bf16 scratch inside the 16 MiB f32 out buffer

    const dim3 blk(256);
    const float iscl = 0.044194173824159216f;   // 1/sqrt(512)

    // act = gelu(emb[tok] @ W1 + b1)   M=8192 N=512 K=256   (A,B f32 -> bf16; C bf16)
    gemm_k<2, true, true, true, false><<<dim3(8, 128, 1), blk, 0, stream>>>(
        emb, W1, b1, act, tok, 8192, 512, 256, 256, 512, 512, 1.0f);
    // q/k/v = act @ W + b              M=8192 N=512 K=512   (A bf16; B f32; C bf16)
    gemm_k<1, true, false, true, false><<<dim3(8, 128, 1), blk, 0, stream>>>(
        act, Wq, bq, q, nullptr, 8192, 512, 512, 512, 512, 512, 1.0f);
    gemm_k<1, true, false, true, false><<<dim3(8, 128, 1), blk, 0, stream>>>(
        act, Wk, bk, k, nullptr, 8192, 512, 512, 512, 512, 512, 1.0f);
    gemm_k<1, true, false, true, false><<<dim3(8, 128, 1), blk, 0, stream>>>(
        act, Wv, bv, v, nullptr, 8192, 512, 512, 512, 512, 512, 1.0f);

    for (int b = 0; b < 4; ++b) {
        const long o = (long)b * 2048 * 512;
        // scores = q_b @ k_b^T / sqrt(512)   M=N=2048 K=512  (bf16 all; B is [N][K] -> BT=false)
        gemm_k<0, false, false, false, false><<<dim3(32, 32, 1), blk, 0, stream>>>(
            q + o, k + o, nullptr, sc, nullptr, 2048, 2048, 512, 512, 512, 2048, iscl);
        // softmax rows
        softmax_k<<<dim3(2048), blk, 0, stream>>>(sc, 2048);
        // out_b = p @ v_b                    M=2048 N=512 K=2048  (A,B bf16; C f32)
        gemm_k<0, true, false, false, true><<<dim3(8, 32, 1), blk, 0, stream>>>(
            sc, v + o, nullptr, out + o * 1, nullptr, 2048, 512, 2048, 2048, 512, 512, 1.0f);
    }
}

// Round 4
// 274.261 us; speedup vs baseline: 1.6768x; 1.6768x over previous
//
#include <hip/hip_runtime.h>
#include <math.h>

// ToyModel: B=4, S=2048, E=256, H=512, VOCAB=50257.
// Inputs/output f32; intermediates bf16; MFMA bf16 w/ f32 accum. posneg == identity.
//
// Structure (round 4):
//   0. transpose_w: W1,Wq,Wk,Wv f32 [K][N] -> bf16 [N][K] (into d_out upper region)
//   1. act = gelu(emb[tok] @ W1 + b1)           bf16 [8192,512] -> d_out (low 8 MiB)
//   2. q,k = act @ W + b                        bf16 [8192,512] -> ws
//      vT  = (act @ Wv + bv)^T per batch       bf16 [4][512][2048] -> ws
//   3. sc = (q @ k^T)/sqrt(512) ; softmax ; out = P @ vT^T  (f32 -> d_out)
//      z-batched over 4 batches if ws_size >= 56 MiB, else per-batch loop (32 MiB).
//
// All GEMMs stage both operands as [row][k] with k-contiguous u16x8 -> no LDS
// bank conflicts (pitch 40 u16 = 20 dwords: 8 distinct bank-starts, 2-way max).

typedef unsigned short u16;
typedef u16   u16x8 __attribute__((ext_vector_type(8)));
typedef short s16x8 __attribute__((ext_vector_type(8)));   // bf16 frag for MFMA
typedef float f32x4 __attribute__((ext_vector_type(4)));
typedef float f32x8 __attribute__((ext_vector_type(8)));

static __device__ __forceinline__ u16 f2bf(float f) {
    unsigned u = __builtin_bit_cast(unsigned, f);
    u = (u + 0x7fffu + ((u >> 16) & 1u)) >> 16;   // RNE
    return (u16)u;
}
static __device__ __forceinline__ float bf2f(u16 h) {
    unsigned u = ((unsigned)h) << 16;
    return __builtin_bit_cast(float, u);
}

struct WArgs {
    const float* src[4];
    u16*         dst[4];
    int          K[4];
};

// f32 W[K][512] -> bf16 WT[512][K]. grid (8, 8, 4); block 256. Early-exit rows >= K.
__launch_bounds__(256)
__global__ void transpose_w_k(WArgs wa)
{
    const int w = blockIdx.z;
    const float* W = wa.src[w];
    u16* WT = wa.dst[w];
    const int K = wa.K[w];
    const int c0 = blockIdx.x * 64;
    const int r0 = blockIdx.y * 64;
    if (r0 >= K) return;

    __shared__ float T[64][65];
    const int t = threadIdx.x;
    const int col = t & 63;
    const int rb  = t >> 6;

#pragma unroll
    for (int i = 0; i < 16; ++i) {
        const int row = i * 4 + rb;
        T[row][col] = W[(long)(r0 + row) * 512 + c0 + col];
    }
    __syncthreads();
#pragma unroll
    for (int i = 0; i < 16; ++i) {
        const int orow = i * 4 + rb;               // output row = source col
        WT[(long)(c0 + orow) * K + r0 + col] = f2bf(T[col][orow]);
    }
}

// 64x64 tile MFMA GEMM, BK=32. Both operands staged [row][k], k-contiguous.
// EPI: 0 = scale, 1 = +bias, 2 = +bias+exact GELU
// AF32: A is f32 global (with optional row gather). VT: write C transposed as
//       vT[batch=row>>11][col][row&2047]. CF32: store f32 (else bf16).
template <int EPI, bool AF32, bool VT, bool CF32>
__launch_bounds__(256)
__global__ void gemm_k(const void* __restrict__ Ap, const u16* __restrict__ Bp,
                       const float* __restrict__ bias, void* __restrict__ Cp,
                       const int* __restrict__ gather,
                       int K, int lda, int ldb, int ldc,
                       long strA, long strB, long strC, float scale)
{
    __shared__ u16 As[64 * 40];
    __shared__ u16 Bs[64 * 40];

    const int bz = blockIdx.z;
    const int m0 = blockIdx.y * 64;
    const int n0 = blockIdx.x * 64;
    const int t    = threadIdx.x;
    const int wid  = t >> 6;
    const int lane = t & 63;
    const int quad = lane >> 4;
    const int l16  = lane & 15;

    f32x4 acc[4] = {};

    const int sr  = t >> 2;          // staging row 0..63
    const int sc8 = (t & 3) * 8;     // staging 8-col group

    long arow;
    {
        const int gr = m0 + sr;
        const int g  = gather ? gather[gr] : gr;
        arow = (long)g * lda + sc8;
    }
    const u16* Abf = AF32 ? nullptr : ((const u16*)Ap + strA * bz);
    const float* Af = AF32 ? (const float*)Ap : nullptr;
    const u16* B = Bp + strB * bz;
    const long brow = (long)(n0 + sr) * ldb + sc8;

    for (int k0 = 0; k0 < K; k0 += 32) {
        u16x8 av;
        if (AF32) {
            f32x8 af = *(const f32x8*)(Af + arow + k0);
#pragma unroll
            for (int i = 0; i < 8; ++i) av[i] = f2bf(af[i]);
        } else {
            av = *(const u16x8*)(Abf + arow + k0);
        }
        *(u16x8*)&As[sr * 40 + sc8] = av;
        *(u16x8*)&Bs[sr * 40 + sc8] = *(const u16x8*)(B + brow + k0);
        __syncthreads();

        const s16x8 a = *(const s16x8*)&As[(wid * 16 + l16) * 40 + quad * 8];
#pragma unroll
        for (int nt = 0; nt < 4; ++nt) {
            const s16x8 b = *(const s16x8*)&Bs[(nt * 16 + l16) * 40 + quad * 8];
            acc[nt] = __builtin_amdgcn_mfma_f32_16x16x32_bf16(a, b, acc[nt], 0, 0, 0);
        }
        __syncthreads();
    }

#pragma unroll
    for (int nt = 0; nt < 4; ++nt) {
        const int col = n0 + nt * 16 + l16;
        const float bval = (EPI >= 1) ? bias[col] : 0.0f;
#pragma unroll
        for (int r = 0; r < 4; ++r) {
            const int row = m0 + wid * 16 + quad * 4 + r;
            float x = acc[nt][r] * scale + bval;
            if (EPI == 2) x = 0.5f * x * (1.0f + erff(x * 0.70710678118654752f));
            if (VT) {
                // vT[batch][col][pos]
                ((u16*)Cp)[(long)(row >> 11) * strC + (long)col * ldc + (row & 2047)] = f2bf(x);
            } else if (CF32) {
                ((float*)Cp + strC * bz)[(long)row * ldc + col] = x;
            } else {
                ((u16*)Cp + strC * bz)[(long)row * ldc + col] = f2bf(x);
            }
        }
    }
}

// One block per score row; softmax in place over S=2048 bf16 columns.
__launch_bounds__(256)
__global__ void softmax_k(u16* __restrict__ sc)
{
    const long base = (long)blockIdx.x * 2048;
    const int t = threadIdx.x;
    const int wid = t >> 6, lane = t & 63;
    __shared__ float redm[4];
    __shared__ float reds[4];

    float v[8];
    float mx = -1e30f;
#pragma unroll
    for (int i = 0; i < 8; ++i) {
        v[i] = bf2f(sc[base + i * 256 + t]);
        mx = fmaxf(mx, v[i]);
    }
#pragma unroll
    for (int off = 32; off; off >>= 1) mx = fmaxf(mx, __shfl_xor(mx, off, 64));
    if (lane == 0) redm[wid] = mx;
    __syncthreads();
    const float bm = fmaxf(fmaxf(redm[0], redm[1]), fmaxf(redm[2], redm[3]));

    float s = 0.0f;
#pragma unroll
    for (int i = 0; i < 8; ++i) { v[i] = expf(v[i] - bm); s += v[i]; }
#pragma unroll
    for (int off = 32; off; off >>= 1) s += __shfl_xor(s, off, 64);
    if (lane == 0) reds[wid] = s;
    __syncthreads();
    const float inv = 1.0f / (reds[0] + reds[1] + reds[2] + reds[3]);

#pragma unroll
    for (int i = 0; i < 8; ++i) sc[base + i * 256 + t] = f2bf(v[i] * inv);
}

extern "C" void kernel_launch(void* const* d_in, const int* in_sizes, int n_in,
                              void* d_out, int out_size, void* d_ws, size_t ws_size,
                              hipStream_t stream)
{
    const int*   tok = (const int*)d_in[0];
    const float* emb = (const float*)d_in[1];
    const float* W1  = (const float*)d_in[2];
    const float* b1  = (const float*)d_in[3];
    const float* Wq  = (const float*)d_in[4];
    const float* bq  = (const float*)d_in[5];
    const float* Wk  = (const float*)d_in[6];
    const float* bk  = (const float*)d_in[7];
    const float* Wv  = (const float*)d_in[8];
    const float* bv  = (const float*)d_in[9];
    float* out = (float*)d_out;

    // d_out doubles as scratch until PV writes: act bf16 (8 MiB) + transposed weights.
    u16* act   = (u16*)d_out;                  // [8192][512] bf16
    u16* wbase = act + 8192l * 512;            // upper 8 MiB of out buffer
    u16* W1T = wbase;                          // [512][256]
    u16* WqT = wbase + 131072;                 // [512][512]
    u16* WkT = wbase + 393216;
    u16* WvT = wbase + 655360;

    char* ws = (char*)d_ws;
    u16* q  = (u16*)(ws);                      // [4][2048][512]
    u16* k  = (u16*)(ws + (8l  << 20));
    u16* vT = (u16*)(ws + (16l << 20));        // [4][512][2048]
    u16* sc = (u16*)(ws + (24l << 20));        // full: 32 MiB; fallback: 8 MiB reused

    const bool full = ws_size >= (56ull << 20);
    const dim3 blk(256);
    const float iscl = 0.044194173824159216f;  // 1/sqrt(512)
    const long  TB = 2048l * 512;              // tokens-per-batch * H
    const long  SS = 2048l * 2048;

    // 0. weight transposes (f32 [K][512] -> bf16 [512][K])
    WArgs wa;
    wa.src[0] = W1; wa.src[1] = Wq; wa.src[2] = Wk; wa.src[3] = Wv;
    wa.dst[0] = W1T; wa.dst[1] = WqT; wa.dst[2] = WkT; wa.dst[3] = WvT;
    wa.K[0] = 256; wa.K[1] = 512; wa.K[2] = 512; wa.K[3] = 512;
    transpose_w_k<<<dim3(8, 8, 4), blk, 0, stream>>>(wa);

    // 1. act = gelu(emb[tok] @ W1 + b1)   M=8192 N=512 K=256
    gemm_k<2, true, false, false><<<dim3(8, 128, 1), blk, 0, stream>>>(
        emb, W1T, b1, act, tok, 256, 256, 256, 512, 0, 0, 0, 1.0f);
    // 2. q,k = act @ W + b ; vT = (act @ Wv + bv)^T   M=8192 N=512 K=512
    gemm_k<1, false, false, false><<<dim3(8, 128, 1), blk, 0, stream>>>(
        act, WqT, bq, q, nullptr, 512, 512, 512, 512, 0, 0, 0, 1.0f);
    gemm_k<1, false, false, false><<<dim3(8, 128, 1), blk, 0, stream>>>(
        act, WkT, bk, k, nullptr, 512, 512, 512, 512, 0, 0, 0, 1.0f);
    gemm_k<1, false, true, false><<<dim3(8, 128, 1), blk, 0, stream>>>(
        act, WvT, bv, vT, nullptr, 512, 512, 512, 2048, 0, 0, TB, 1.0f);

    if (full) {
        // 3. attention, z-batched over 4 batches
        gemm_k<0, false, false, false><<<dim3(32, 32, 4), blk, 0, stream>>>(
            q, k, nullptr, sc, nullptr, 512, 512, 512, 2048, TB, TB, SS, iscl);
        softmax_k<<<dim3(8192), blk, 0, stream>>>(sc);
        gemm_k<0, false, false, true><<<dim3(8, 32, 4), blk, 0, stream>>>(
            sc, vT, nullptr, out, nullptr, 2048, 2048, 2048, 512, SS, TB, TB, 1.0f);
    } else {
        for (int b = 0; b < 4; ++b) {
            gemm_k<0, false, false, false><<<dim3(32, 32, 1), blk, 0, stream>>>(
                q + b * TB, k + b * TB, nullptr, sc, nullptr,
                512, 512, 512, 2048, 0, 0, 0, iscl);
            softmax_k<<<dim3(2048), blk, 0, stream>>>(sc);
            gemm_k<0, false, false, true><<<dim3(8, 32, 1), blk, 0, stream>>>(
                sc, vT + b * TB, nullptr, out + b * TB, nullptr,
                2048, 2048, 2048, 512, 0, 0, 0, 1.0f);
        }
    }
}

// Round 5
// 241.401 us; speedup vs baseline: 1.9051x; 1.1361x over previous
//
#include <hip/hip_runtime.h>
#include <math.h>

// ToyModel: B=4, S=2048, E=256, H=512, VOCAB=50257.
// Inputs/output f32; intermediates bf16; MFMA bf16 w/ f32 accum. posneg == identity.
//
// Round 5: m97-style GEMM — global_load_lds width-16 staging into unpadded
// LDS [row][32] tiles, 128-wide n-tile, TM templated (64/128 m-tile).
//
//   0a. embB = bf16(emb[tok])                  [8192,256]  -> ws+24MiB (dead before sc)
//   0b. W1,Wq,Wk,Wv f32 [K][512] -> bf16 [512][K] (d_out upper half, dead before PV)
//   1. act = gelu(embB @ W1T + b1)             bf16 [8192,512] -> d_out low 8 MiB
//   2. q,k = act @ W + b ; vT = (act @ Wv+bv)^T   -> ws
//   3. sc = (q @ k^T)/sqrt(512); softmax; out = P @ vT^T (f32)
//
// ws: q@0 | k@8MiB | vT@16MiB | sc@24MiB (32MiB, z=4)  == 56 MiB (proven in r4).

typedef unsigned short u16;
typedef u16   u16x8 __attribute__((ext_vector_type(8)));
typedef short s16x8 __attribute__((ext_vector_type(8)));
typedef float f32x4 __attribute__((ext_vector_type(4)));
typedef float f32x8 __attribute__((ext_vector_type(8)));

static __device__ __forceinline__ u16 f2bf(float f) {
    unsigned u = __builtin_bit_cast(unsigned, f);
    u = (u + 0x7fffu + ((u >> 16) & 1u)) >> 16;   // RNE
    return (u16)u;
}
static __device__ __forceinline__ float bf2f(u16 h) {
    unsigned u = ((unsigned)h) << 16;
    return __builtin_bit_cast(float, u);
}

// Async 16-B/lane global->LDS. LDS dest is wave-uniform base + lane*16.
static __device__ __forceinline__ void gload_lds16(const u16* g, u16* l) {
    __builtin_amdgcn_global_load_lds(
        (const __attribute__((address_space(1))) void*)g,
        (__attribute__((address_space(3))) void*)l, 16, 0, 0);
}

// ---- gather + f32->bf16 convert of embedding rows: dst[8192][256] ----
__launch_bounds__(256)
__global__ void cvt_gather_k(const float* __restrict__ emb, const int* __restrict__ tok,
                             u16* __restrict__ dst)
{
    const int t = blockIdx.x * 256 + threadIdx.x;   // 0..262143
    const int row = t >> 5;                         // 32 chunks of 8 per row
    const int c8  = (t & 31) * 8;
    f32x8 v = *(const f32x8*)(emb + (long)tok[row] * 256 + c8);
    u16x8 o;
#pragma unroll
    for (int j = 0; j < 8; ++j) o[j] = f2bf(v[j]);
    *(u16x8*)(dst + (long)row * 256 + c8) = o;
}

struct WArgs {
    const float* src[4];
    u16*         dst[4];
    int          K[4];
};

// f32 W[K][512] -> bf16 WT[512][K]. grid (8, 8, 4); block 256.
__launch_bounds__(256)
__global__ void transpose_w_k(WArgs wa)
{
    const int w = blockIdx.z;
    const float* W = wa.src[w];
    u16* WT = wa.dst[w];
    const int K = wa.K[w];
    const int c0 = blockIdx.x * 64;
    const int r0 = blockIdx.y * 64;
    if (r0 >= K) return;

    __shared__ float T[64][65];
    const int t = threadIdx.x;
    const int col = t & 63;
    const int rb  = t >> 6;

#pragma unroll
    for (int i = 0; i < 16; ++i)
        T[i * 4 + rb][col] = W[(long)(r0 + i * 4 + rb) * 512 + c0 + col];
    __syncthreads();
#pragma unroll
    for (int i = 0; i < 16; ++i) {
        const int orow = i * 4 + rb;
        WT[(long)(c0 + orow) * K + r0 + col] = f2bf(T[col][orow]);
    }
}

// ---- m97-style MFMA GEMM: BM = TM*32 (64|128), BN = 128, BK = 32 ----
// 4 waves in 2x2; each wave TM x 4 grid of 16x16x32 MFMAs.
// A,B bf16, B pre-transposed [n][k]. EPI: 0 scale, 1 +bias, 2 +bias+GELU.
// VT: write C^T as vT[row>>11][col][row&2047]. CF32: f32 C else bf16.
template <int TM, int EPI, bool VT, bool CF32>
__launch_bounds__(256)
__global__ void gemm128(const u16* __restrict__ A, const u16* __restrict__ B,
                        const float* __restrict__ bias, void* __restrict__ C,
                        int K, int lda, int ldb, int ldc,
                        long strA, long strB, long strC, float scale)
{
    constexpr int BM = TM * 32;
    __shared__ u16 As[BM * 32];     // [m][k], unpadded (global_load_lds layout)
    __shared__ u16 Bs[128 * 32];    // [n][k]

    const int bz = blockIdx.z;
    A += strA * bz; B += strB * bz;

    const int m0 = blockIdx.y * BM;
    const int n0 = blockIdx.x * 128;
    const int t = threadIdx.x;
    const int w = t >> 6;
    const int lane = t & 63;
    const int quad = lane >> 4;
    const int l16  = lane & 15;
    const int wm = w >> 1, wn = w & 1;

    f32x4 acc[TM][4] = {};

    // staging: lane covers LDS bytes (w*1024 + r*4096 + lane*16)
    //   -> element w*512 + r*2048 + 8*lane -> row w*16 + r*64 + lane/4, kchunk (lane&3)*8
    const int srow = w * 16 + (lane >> 2);
    const int skc  = (lane & 3) * 8;
    const u16* ga = A + (long)(m0 + srow) * lda + skc;
    const u16* gb = B + (long)(n0 + srow) * ldb + skc;
    u16* lA = &As[w * 512];
    u16* lB = &Bs[w * 512];
    const long a64 = (long)64 * lda;
    const long b64 = (long)64 * ldb;

    for (int k0 = 0; k0 < K; k0 += 32) {
        gload_lds16(ga + k0, lA);
        if (TM == 4) gload_lds16(ga + a64 + k0, lA + 2048);
        gload_lds16(gb + k0, lB);
        gload_lds16(gb + b64 + k0, lB + 2048);
        __syncthreads();   // drains vmcnt (global_load_lds) before reads

        s16x8 af[TM], bf[4];
#pragma unroll
        for (int x = 0; x < TM; ++x)
            af[x] = *(const s16x8*)&As[(wm * (TM * 16) + x * 16 + l16) * 32 + quad * 8];
#pragma unroll
        for (int y = 0; y < 4; ++y)
            bf[y] = *(const s16x8*)&Bs[(wn * 64 + y * 16 + l16) * 32 + quad * 8];
#pragma unroll
        for (int x = 0; x < TM; ++x)
#pragma unroll
            for (int y = 0; y < 4; ++y)
                acc[x][y] = __builtin_amdgcn_mfma_f32_16x16x32_bf16(af[x], bf[y], acc[x][y], 0, 0, 0);
        __syncthreads();
    }

#pragma unroll
    for (int y = 0; y < 4; ++y) {
        const int col = n0 + wn * 64 + y * 16 + l16;
        const float bval = (EPI >= 1) ? bias[col] : 0.0f;
#pragma unroll
        for (int x = 0; x < TM; ++x) {
#pragma unroll
            for (int r = 0; r < 4; ++r) {
                const int row = m0 + wm * (TM * 16) + x * 16 + quad * 4 + r;
                float v = acc[x][y][r] * scale + bval;
                if (EPI == 2) v = 0.5f * v * (1.0f + erff(v * 0.70710678118654752f));
                if (VT)
                    ((u16*)C)[(long)(row >> 11) * strC + (long)col * ldc + (row & 2047)] = f2bf(v);
                else if (CF32)
                    ((float*)C + strC * bz)[(long)row * ldc + col] = v;
                else
                    ((u16*)C + strC * bz)[(long)row * ldc + col] = f2bf(v);
            }
        }
    }
}

// One block per score row; softmax in place over 2048 bf16 columns.
__launch_bounds__(256)
__global__ void softmax_k(u16* __restrict__ sc)
{
    const long base = (long)blockIdx.x * 2048;
    const int t = threadIdx.x;
    const int wid = t >> 6, lane = t & 63;
    __shared__ float redm[4];
    __shared__ float reds[4];

    float v[8];
    float mx = -1e30f;
#pragma unroll
    for (int i = 0; i < 8; ++i) {
        v[i] = bf2f(sc[base + i * 256 + t]);
        mx = fmaxf(mx, v[i]);
    }
#pragma unroll
    for (int off = 32; off; off >>= 1) mx = fmaxf(mx, __shfl_xor(mx, off, 64));
    if (lane == 0) redm[wid] = mx;
    __syncthreads();
    const float bm = fmaxf(fmaxf(redm[0], redm[1]), fmaxf(redm[2], redm[3]));

    float s = 0.0f;
#pragma unroll
    for (int i = 0; i < 8; ++i) { v[i] = expf(v[i] - bm); s += v[i]; }
#pragma unroll
    for (int off = 32; off; off >>= 1) s += __shfl_xor(s, off, 64);
    if (lane == 0) reds[wid] = s;
    __syncthreads();
    const float inv = 1.0f / (reds[0] + reds[1] + reds[2] + reds[3]);

#pragma unroll
    for (int i = 0; i < 8; ++i) sc[base + i * 256 + t] = f2bf(v[i] * inv);
}

extern "C" void kernel_launch(void* const* d_in, const int* in_sizes, int n_in,
                              void* d_out, int out_size, void* d_ws, size_t ws_size,
                              hipStream_t stream)
{
    const int*   tok = (const int*)d_in[0];
    const float* emb = (const float*)d_in[1];
    const float* W1  = (const float*)d_in[2];
    const float* b1  = (const float*)d_in[3];
    const float* Wq  = (const float*)d_in[4];
    const float* bq  = (const float*)d_in[5];
    const float* Wk  = (const float*)d_in[6];
    const float* bk  = (const float*)d_in[7];
    const float* Wv  = (const float*)d_in[8];
    const float* bv  = (const float*)d_in[9];
    float* out = (float*)d_out;

    // d_out doubles as scratch until PV writes.
    u16* act   = (u16*)d_out;                  // [8192][512] bf16 (8 MiB)
    u16* wbase = act + 8192l * 512;
    u16* W1T = wbase;                          // [512][256]
    u16* WqT = wbase + 131072;                 // [512][512]
    u16* WkT = wbase + 393216;
    u16* WvT = wbase + 655360;

    char* ws = (char*)d_ws;
    u16* q    = (u16*)(ws);                    // [4][2048][512]
    u16* k    = (u16*)(ws + (8l  << 20));
    u16* vT   = (u16*)(ws + (16l << 20));      // [4][512][2048]
    u16* sc   = (u16*)(ws + (24l << 20));      // [4][2048][2048] bf16 (32 MiB)
    u16* embB = sc;                            // [8192][256] bf16, dead before sc written

    const dim3 blk(256);
    const float iscl = 0.044194173824159216f;  // 1/sqrt(512)
    const long  TB = 2048l * 512;
    const long  SS = 2048l * 2048;

    // 0a. gathered embedding rows -> bf16
    cvt_gather_k<<<dim3(1024), blk, 0, stream>>>(emb, tok, embB);
    // 0b. weight transposes
    WArgs wa;
    wa.src[0] = W1; wa.src[1] = Wq; wa.src[2] = Wk; wa.src[3] = Wv;
    wa.dst[0] = W1T; wa.dst[1] = WqT; wa.dst[2] = WkT; wa.dst[3] = WvT;
    wa.K[0] = 256; wa.K[1] = 512; wa.K[2] = 512; wa.K[3] = 512;
    transpose_w_k<<<dim3(8, 8, 4), blk, 0, stream>>>(wa);

    // 1. act = gelu(embB @ W1T + b1)   M=8192 N=512 K=256  (TM=2 -> 512 blocks)
    gemm128<2, 2, false, false><<<dim3(4, 128, 1), blk, 0, stream>>>(
        embB, W1T, b1, act, 256, 256, 256, 512, 0, 0, 0, 1.0f);
    // 2. q,k,vT   M=8192 N=512 K=512
    gemm128<2, 1, false, false><<<dim3(4, 128, 1), blk, 0, stream>>>(
        act, WqT, bq, q, 512, 512, 512, 512, 0, 0, 0, 1.0f);
    gemm128<2, 1, false, false><<<dim3(4, 128, 1), blk, 0, stream>>>(
        act, WkT, bk, k, 512, 512, 512, 512, 0, 0, 0, 1.0f);
    gemm128<2, 1, true, false><<<dim3(4, 128, 1), blk, 0, stream>>>(
        act, WvT, bv, vT, 512, 512, 512, 2048, 0, 0, TB, 1.0f);

    // 3. attention (z = batch)
    //    sc = q @ k^T / sqrt(512)   M=N=2048 K=512  (TM=4 -> 1024 blocks)
    gemm128<4, 0, false, false><<<dim3(16, 16, 4), blk, 0, stream>>>(
        q, k, nullptr, sc, 512, 512, 512, 2048, TB, TB, SS, iscl);
    softmax_k<<<dim3(8192), blk, 0, stream>>>(sc);
    //    out = P @ vT^T   M=2048 N=512 K=2048  (TM=2 -> 512 blocks)
    gemm128<2, 0, false, true><<<dim3(4, 32, 4), blk, 0, stream>>>(
        sc, vT, nullptr, out, 2048, 2048, 2048, 512, SS, TB, TB, 1.0f);
}

// Round 6
// 239.544 us; speedup vs baseline: 1.9199x; 1.0078x over previous
//
#include <hip/hip_runtime.h>
#include <math.h>

// ToyModel: B=4, S=2048, E=256, H=512, VOCAB=50257.
// Inputs/output f32; intermediates bf16; MFMA bf16 w/ f32 accum. posneg == identity.
//
// Round 6: double-buffered global_load_lds K-loop (1 barrier/iter), fused QKV
// GEMM (N=1536), split-K x2 PV with m-fastest grid order + add pass.
//
//   0a. embB = bf16(emb[tok])                 [8192,256]  -> ws+24MiB (dead before sc)
//   0b. W1,Wq,Wk,Wv f32 [K][512] -> bf16 [512][K] contiguous (d_out upper, dead before PV)
//   1. act = gelu(embB @ W1T + b1)            bf16 [8192,512] -> d_out low 8 MiB
//   2. fused: q,k = act @ W + b ; vT = (act @ Wv+bv)^T  -> ws   (one GEMM, N=1536)
//   3. sc = (q @ k^T)/sqrt(512); softmax
//   4. out = P @ vT^T  split-K x2: kh0 -> out f32, kh1 -> wsP (q/k region, dead); out += wsP
//
// ws: q@0 | k@8MiB | vT@16MiB | sc@24MiB(32MiB) = 56 MiB. wsP aliases q+k (16MiB).

typedef unsigned short u16;
typedef u16   u16x8 __attribute__((ext_vector_type(8)));
typedef short s16x8 __attribute__((ext_vector_type(8)));
typedef float f32x4 __attribute__((ext_vector_type(4)));
typedef float f32x8 __attribute__((ext_vector_type(8)));

static __device__ __forceinline__ u16 f2bf(float f) {
    unsigned u = __builtin_bit_cast(unsigned, f);
    u = (u + 0x7fffu + ((u >> 16) & 1u)) >> 16;   // RNE
    return (u16)u;
}
static __device__ __forceinline__ float bf2f(u16 h) {
    unsigned u = ((unsigned)h) << 16;
    return __builtin_bit_cast(float, u);
}

static __device__ __forceinline__ void gload_lds16(const u16* g, u16* l) {
    __builtin_amdgcn_global_load_lds(
        (const __attribute__((address_space(1))) void*)g,
        (__attribute__((address_space(3))) void*)l, 16, 0, 0);
}

// ---- gather + f32->bf16 convert of embedding rows: dst[8192][256] ----
__launch_bounds__(256)
__global__ void cvt_gather_k(const float* __restrict__ emb, const int* __restrict__ tok,
                             u16* __restrict__ dst)
{
    const int t = blockIdx.x * 256 + threadIdx.x;
    const int row = t >> 5;
    const int c8  = (t & 31) * 8;
    f32x8 v = *(const f32x8*)(emb + (long)tok[row] * 256 + c8);
    u16x8 o;
#pragma unroll
    for (int j = 0; j < 8; ++j) o[j] = f2bf(v[j]);
    *(u16x8*)(dst + (long)row * 256 + c8) = o;
}

struct WArgs {
    const float* src[4];
    u16*         dst[4];
    int          K[4];
};

// f32 W[K][512] -> bf16 WT[512][K]. grid (8, 8, 4); block 256.
__launch_bounds__(256)
__global__ void transpose_w_k(WArgs wa)
{
    const int w = blockIdx.z;
    const float* W = wa.src[w];
    u16* WT = wa.dst[w];
    const int K = wa.K[w];
    const int c0 = blockIdx.x * 64;
    const int r0 = blockIdx.y * 64;
    if (r0 >= K) return;

    __shared__ float T[64][65];
    const int t = threadIdx.x;
    const int col = t & 63;
    const int rb  = t >> 6;

#pragma unroll
    for (int i = 0; i < 16; ++i)
        T[i * 4 + rb][col] = W[(long)(r0 + i * 4 + rb) * 512 + c0 + col];
    __syncthreads();
#pragma unroll
    for (int i = 0; i < 16; ++i) {
        const int orow = i * 4 + rb;
        WT[(long)(c0 + orow) * K + r0 + col] = f2bf(T[col][orow]);
    }
}

struct GArgs {
    const u16* A; const u16* B; const float* bias; void* C;
    float* Cpart;                         // split-K partial (kh=1)
    u16 *qd, *kd, *vTd;                   // QKV-fused epilogue dsts
    const float *bq, *bk, *bv;
    int K, lda, ldb, ldc;
    long strA, strB, strC;
    float scale;
};

// m97-style MFMA GEMM w/ double-buffered async staging. BM=TM*32, BN=128, BK=32.
// TM in {2,4}. EPI: 0 scale, 1 +bias, 2 +bias+GELU.
// CMODE: 0 bf16 C, 1 f32 C, 2 QKV-fused (cols<512->q, <1024->k, else vT transposed).
// MX: m-tile in blockIdx.x (fastest) for B-tile L2 reuse. SPLITK: z = batch*2+kh, K=1024.
template <int TM, int EPI, int CMODE, bool MX, bool SPLITK>
__launch_bounds__(256)
__global__ void gemm128(GArgs g)
{
    constexpr int BM  = TM * 32;
    constexpr int ASZ = BM * 32;
    constexpr int BSZ = 128 * 32;
    __shared__ u16 As[2 * ASZ];
    __shared__ u16 Bs[2 * BSZ];

    const int bz    = blockIdx.z;
    const int batch = SPLITK ? (bz >> 1) : bz;
    const int kh    = SPLITK ? (bz & 1) : 0;
    const u16* A = g.A + g.strA * batch + (SPLITK ? kh * 1024 : 0);
    const u16* B = g.B + g.strB * batch + (SPLITK ? kh * 1024 : 0);

    const int m0 = (MX ? blockIdx.x : blockIdx.y) * BM;
    const int n0 = (MX ? blockIdx.y : blockIdx.x) * 128;
    const int t = threadIdx.x;
    const int w = t >> 6;
    const int lane = t & 63;
    const int quad = lane >> 4;
    const int l16  = lane & 15;
    const int wm = w >> 1, wn = w & 1;

    // staging: wave w covers rows w*16+lane/4, k-chunk (lane&3)*8, per 64-row group
    const int srow = w * 16 + (lane >> 2);
    const int skc  = (lane & 3) * 8;
    const u16* ga = A + (long)(m0 + srow) * g.lda + skc;
    const u16* gb = B + (long)(n0 + srow) * g.ldb + skc;
    const long a64 = (long)64 * g.lda;
    const long b64 = (long)64 * g.ldb;
    u16* lA = As + w * 512;
    u16* lB = Bs + w * 512;

    auto stage = [&](int buf, int k0) {
        u16* la = lA + buf * ASZ;
        u16* lb = lB + buf * BSZ;
        gload_lds16(ga + k0, la);
        if (TM == 4) gload_lds16(ga + a64 + k0, la + 2048);
        gload_lds16(gb + k0, lb);
        gload_lds16(gb + b64 + k0, lb + 2048);
    };

    f32x4 acc[TM][4] = {};
    const int K = SPLITK ? 1024 : g.K;

    stage(0, 0);
    int cur = 0;
    for (int k0 = 0; k0 < K; k0 += 32) {
        __syncthreads();                       // drains vmcnt: buf[cur] ready
        if (k0 + 32 < K) stage(cur ^ 1, k0 + 32);   // in flight during compute

        const u16* as = As + cur * ASZ;
        const u16* bs = Bs + cur * BSZ;
        s16x8 af[TM], bf[4];
#pragma unroll
        for (int x = 0; x < TM; ++x)
            af[x] = *(const s16x8*)&as[(wm * (TM * 16) + x * 16 + l16) * 32 + quad * 8];
#pragma unroll
        for (int y = 0; y < 4; ++y)
            bf[y] = *(const s16x8*)&bs[(wn * 64 + y * 16 + l16) * 32 + quad * 8];
#pragma unroll
        for (int x = 0; x < TM; ++x)
#pragma unroll
            for (int y = 0; y < 4; ++y)
                acc[x][y] = __builtin_amdgcn_mfma_f32_16x16x32_bf16(af[x], bf[y], acc[x][y], 0, 0, 0);
        cur ^= 1;
    }

#pragma unroll
    for (int y = 0; y < 4; ++y) {
        const int col = n0 + wn * 64 + y * 16 + l16;
        float bval = 0.0f;
        if (CMODE == 2)
            bval = col < 512 ? g.bq[col] : (col < 1024 ? g.bk[col - 512] : g.bv[col - 1024]);
        else if (EPI >= 1)
            bval = g.bias[col];
#pragma unroll
        for (int x = 0; x < TM; ++x) {
#pragma unroll
            for (int r = 0; r < 4; ++r) {
                const int row = m0 + wm * (TM * 16) + x * 16 + quad * 4 + r;
                float v = acc[x][y][r] * g.scale + bval;
                if (EPI == 2) v = 0.5f * v * (1.0f + erff(v * 0.70710678118654752f));
                if (CMODE == 2) {
                    if (col < 512)
                        g.qd[(long)row * 512 + col] = f2bf(v);
                    else if (col < 1024)
                        g.kd[(long)row * 512 + (col - 512)] = f2bf(v);
                    else
                        g.vTd[(long)(row >> 11) * (2048l * 512) + (long)(col - 1024) * 2048 + (row & 2047)] = f2bf(v);
                } else if (SPLITK) {
                    float* dst = kh ? g.Cpart : (float*)g.C;
                    dst[g.strC * batch + (long)row * g.ldc + col] = v;
                } else if (CMODE == 1) {
                    ((float*)g.C + g.strC * batch)[(long)row * g.ldc + col] = v;
                } else {
                    ((u16*)g.C + g.strC * batch)[(long)row * g.ldc + col] = f2bf(v);
                }
            }
        }
    }
}

// One block per score row; softmax in place over 2048 bf16 columns.
__launch_bounds__(256)
__global__ void softmax_k(u16* __restrict__ sc)
{
    const long base = (long)blockIdx.x * 2048;
    const int t = threadIdx.x;
    const int wid = t >> 6, lane = t & 63;
    __shared__ float redm[4];
    __shared__ float reds[4];

    float v[8];
    float mx = -1e30f;
#pragma unroll
    for (int i = 0; i < 8; ++i) {
        v[i] = bf2f(sc[base + i * 256 + t]);
        mx = fmaxf(mx, v[i]);
    }
#pragma unroll
    for (int off = 32; off; off >>= 1) mx = fmaxf(mx, __shfl_xor(mx, off, 64));
    if (lane == 0) redm[wid] = mx;
    __syncthreads();
    const float bm = fmaxf(fmaxf(redm[0], redm[1]), fmaxf(redm[2], redm[3]));

    float s = 0.0f;
#pragma unroll
    for (int i = 0; i < 8; ++i) { v[i] = expf(v[i] - bm); s += v[i]; }
#pragma unroll
    for (int off = 32; off; off >>= 1) s += __shfl_xor(s, off, 64);
    if (lane == 0) reds[wid] = s;
    __syncthreads();
    const float inv = 1.0f / (reds[0] + reds[1] + reds[2] + reds[3]);

#pragma unroll
    for (int i = 0; i < 8; ++i) sc[base + i * 256 + t] = f2bf(v[i] * inv);
}

// out[i] += part[i], f32x4 per thread. grid 4096 x 256 covers 4*2048*512 floats.
__launch_bounds__(256)
__global__ void add_k(float* __restrict__ out, const float* __restrict__ part)
{
    const long i = ((long)blockIdx.x * 256 + threadIdx.x) * 4;
    f32x4 a = *(const f32x4*)(out + i);
    f32x4 b = *(const f32x4*)(part + i);
    a += b;
    *(f32x4*)(out + i) = a;
}

extern "C" void kernel_launch(void* const* d_in, const int* in_sizes, int n_in,
                              void* d_out, int out_size, void* d_ws, size_t ws_size,
                              hipStream_t stream)
{
    const int*   tok = (const int*)d_in[0];
    const float* emb = (const float*)d_in[1];
    const float* W1  = (const float*)d_in[2];
    const float* b1  = (const float*)d_in[3];
    const float* Wq  = (const float*)d_in[4];
    const float* bq  = (const float*)d_in[5];
    const float* Wk  = (const float*)d_in[6];
    const float* bk  = (const float*)d_in[7];
    const float* Wv  = (const float*)d_in[8];
    const float* bv  = (const float*)d_in[9];
    float* out = (float*)d_out;

    // d_out doubles as scratch until PV writes.
    u16* act   = (u16*)d_out;                  // [8192][512] bf16 (8 MiB)
    u16* wbase = act + 8192l * 512;
    u16* W1T = wbase;                          // [512][256]
    u16* WqT = wbase + 131072;                 // [1536][512] contiguous (q,k,v)
    u16* WkT = WqT + 262144;
    u16* WvT = WkT + 262144;

    char* ws = (char*)d_ws;
    u16* q    = (u16*)(ws);                    // [4][2048][512]
    u16* k    = (u16*)(ws + (8l  << 20));
    u16* vT   = (u16*)(ws + (16l << 20));      // [4][512][2048]
    u16* sc   = (u16*)(ws + (24l << 20));      // [4][2048][2048] bf16 (32 MiB)
    u16* embB = sc;                            // dead before sc written
    float* wsP = (float*)ws;                   // 16 MiB partial, aliases q+k (dead by PV)

    const dim3 blk(256);
    const float iscl = 0.044194173824159216f;  // 1/sqrt(512)
    const long  TB = 2048l * 512;
    const long  SS = 2048l * 2048;

    // 0a. gathered embedding rows -> bf16
    cvt_gather_k<<<dim3(1024), blk, 0, stream>>>(emb, tok, embB);
    // 0b. weight transposes (WqT/WkT/WvT contiguous -> one [1536][512] matrix)
    WArgs wa;
    wa.src[0] = W1; wa.src[1] = Wq; wa.src[2] = Wk; wa.src[3] = Wv;
    wa.dst[0] = W1T; wa.dst[1] = WqT; wa.dst[2] = WkT; wa.dst[3] = WvT;
    wa.K[0] = 256; wa.K[1] = 512; wa.K[2] = 512; wa.K[3] = 512;
    transpose_w_k<<<dim3(8, 8, 4), blk, 0, stream>>>(wa);

    // 1. act = gelu(embB @ W1T + b1)   M=8192 N=512 K=256
    {
        GArgs a = {};
        a.A = embB; a.B = W1T; a.bias = b1; a.C = act;
        a.K = 256; a.lda = 256; a.ldb = 256; a.ldc = 512; a.scale = 1.0f;
        gemm128<2, 2, 0, false, false><<<dim3(4, 128, 1), blk, 0, stream>>>(a);
    }
    // 2. fused QKV: [q|k|vT] = act @ [Wq|Wk|Wv]^T + b   M=8192 N=1536 K=512
    {
        GArgs a = {};
        a.A = act; a.B = WqT; a.K = 512; a.lda = 512; a.ldb = 512; a.scale = 1.0f;
        a.qd = q; a.kd = k; a.vTd = vT; a.bq = bq; a.bk = bk; a.bv = bv;
        gemm128<2, 0, 2, false, false><<<dim3(12, 128, 1), blk, 0, stream>>>(a);
    }
    // 3. sc = q @ k^T / sqrt(512)   M=N=2048 K=512, z=batch
    {
        GArgs a = {};
        a.A = q; a.B = k; a.C = sc;
        a.K = 512; a.lda = 512; a.ldb = 512; a.ldc = 2048;
        a.strA = TB; a.strB = TB; a.strC = SS; a.scale = iscl;
        gemm128<4, 0, 0, false, false><<<dim3(16, 16, 4), blk, 0, stream>>>(a);
    }
    softmax_k<<<dim3(8192), blk, 0, stream>>>(sc);
    // 4. out = P @ vT^T  M=2048 N=512 K=2048, split-K x2, m-fastest grid
    {
        GArgs a = {};
        a.A = sc; a.B = vT; a.C = out; a.Cpart = wsP;
        a.K = 2048; a.lda = 2048; a.ldb = 2048; a.ldc = 512;
        a.strA = SS; a.strB = TB; a.strC = TB; a.scale = 1.0f;
        gemm128<2, 0, 1, true, true><<<dim3(32, 4, 8), blk, 0, stream>>>(a);
    }
    add_k<<<dim3(4096), blk, 0, stream>>>(out, wsP);
}

// Round 7
// 231.376 us; speedup vs baseline: 1.9876x; 1.0353x over previous
//
#include <hip/hip_runtime.h>
#include <math.h>

// ToyModel: B=4, S=2048, E=256, H=512, VOCAB=50257.
// Inputs/output f32; intermediates bf16; MFMA bf16 w/ f32 accum. posneg == identity.
//
// Round 7: XCD-aligned m-stripe swizzle (cvt_gather/GEMM1/QKV share stripes so
// act stays in the producing XCD's L2), QKV writes q,k,v row-major (coalesced),
// separate LDS-tiled v->vT transpose. QK/softmax/PV unchanged from round 6.
//
// ws: q@0 | k@8MiB | vT@16MiB | sc@24MiB(32MiB) = 56 MiB. v(row-major) aliases
// sc's first 8 MiB until transpose_v consumes it; wsP aliases q+k for split-K.

typedef unsigned short u16;
typedef u16   u16x8 __attribute__((ext_vector_type(8)));
typedef short s16x8 __attribute__((ext_vector_type(8)));
typedef float f32x4 __attribute__((ext_vector_type(4)));
typedef float f32x8 __attribute__((ext_vector_type(8)));

static __device__ __forceinline__ u16 f2bf(float f) {
    unsigned u = __builtin_bit_cast(unsigned, f);
    u = (u + 0x7fffu + ((u >> 16) & 1u)) >> 16;   // RNE
    return (u16)u;
}
static __device__ __forceinline__ float bf2f(u16 h) {
    unsigned u = ((unsigned)h) << 16;
    return __builtin_bit_cast(float, u);
}

static __device__ __forceinline__ void gload_lds16(const u16* g, u16* l) {
    __builtin_amdgcn_global_load_lds(
        (const __attribute__((address_space(1))) void*)g,
        (__attribute__((address_space(3))) void*)l, 16, 0, 0);
}

// ---- gather + f32->bf16 of embedding rows, XCD-striped: block b (xcd=b&7)
// writes rows [xcd*1024 + (b>>3)*8, +8) so GEMM1's stripe-x reads hit own L2.
__launch_bounds__(256)
__global__ void cvt_gather_k(const float* __restrict__ emb, const int* __restrict__ tok,
                             u16* __restrict__ dst)
{
    const int b = blockIdx.x;
    const int g = (b & 7) * 128 + (b >> 3);         // row-group 0..1023
    const int t = g * 2048 + threadIdx.x * 8;       // elem offset in [8192*256]
    const int row = t >> 8;
    const int c8  = t & 255;
    f32x8 v = *(const f32x8*)(emb + (long)tok[row] * 256 + c8);
    u16x8 o;
#pragma unroll
    for (int j = 0; j < 8; ++j) o[j] = f2bf(v[j]);
    *(u16x8*)(dst + (long)row * 256 + c8) = o;
}

struct WArgs {
    const float* src[4];
    u16*         dst[4];
    int          K[4];
};

// f32 W[K][512] -> bf16 WT[512][K]. grid (8, 8, 4); block 256.
__launch_bounds__(256)
__global__ void transpose_w_k(WArgs wa)
{
    const int w = blockIdx.z;
    const float* W = wa.src[w];
    u16* WT = wa.dst[w];
    const int K = wa.K[w];
    const int c0 = blockIdx.x * 64;
    const int r0 = blockIdx.y * 64;
    if (r0 >= K) return;

    __shared__ float T[64][65];
    const int t = threadIdx.x;
    const int col = t & 63;
    const int rb  = t >> 6;

#pragma unroll
    for (int i = 0; i < 16; ++i)
        T[i * 4 + rb][col] = W[(long)(r0 + i * 4 + rb) * 512 + c0 + col];
    __syncthreads();
#pragma unroll
    for (int i = 0; i < 16; ++i) {
        const int orow = i * 4 + rb;
        WT[(long)(c0 + orow) * K + r0 + col] = f2bf(T[col][orow]);
    }
}

// bf16 v[4*2048][512] -> vT[4][512][2048]. grid (8 h-tiles, 32 tok-tiles, 4).
__launch_bounds__(256)
__global__ void transpose_v_k(const u16* __restrict__ v, u16* __restrict__ vT)
{
    const int b  = blockIdx.z;
    const int h0 = blockIdx.x * 64;
    const int t0 = blockIdx.y * 64;

    __shared__ u16 T[64][65];
    const int t = threadIdx.x;
    const int col = t & 63;
    const int rb  = t >> 6;

#pragma unroll
    for (int i = 0; i < 16; ++i) {
        const int row = i * 4 + rb;
        T[row][col] = v[(long)(b * 2048 + t0 + row) * 512 + h0 + col];
    }
    __syncthreads();
#pragma unroll
    for (int i = 0; i < 16; ++i) {
        const int orow = i * 4 + rb;
        vT[(long)b * (512 * 2048) + (long)(h0 + orow) * 2048 + t0 + col] = T[col][orow];
    }
}

struct GArgs {
    const u16* A; const u16* B; const float* bias; void* C;
    float* Cpart;                         // split-K partial (kh=1)
    u16 *qd, *kd, *vd;                    // QKV-fused epilogue dsts (all row-major)
    const float *bq, *bk, *bv;
    int K, lda, ldb, ldc;
    long strA, strB, strC;
    float scale;
};

// MFMA GEMM w/ double-buffered async staging. BM=TM*32, BN=128, BK=32.
// TM in {2,4}. EPI: 0 scale, 1 +bias, 2 +bias+GELU.
// CMODE: 0 bf16 C, 1 f32 C, 2 QKV-fused (cols<512->q, <1024->k, else v; row-major).
// MX: m-tile fastest (B-tile L2 reuse). SPLITK: z = batch*2+kh, K=1024.
// XSW: XCD m-stripe swizzle — lid%8 selects XCD-stripe of gridDim.y/8 m-tiles.
template <int TM, int EPI, int CMODE, bool MX, bool SPLITK, bool XSW>
__launch_bounds__(256)
__global__ void gemm128(GArgs g)
{
    constexpr int BM  = TM * 32;
    constexpr int ASZ = BM * 32;
    constexpr int BSZ = 128 * 32;
    __shared__ u16 As[2 * ASZ];
    __shared__ u16 Bs[2 * BSZ];

    const int bz    = blockIdx.z;
    const int batch = SPLITK ? (bz >> 1) : bz;
    const int kh    = SPLITK ? (bz & 1) : 0;
    const u16* A = g.A + g.strA * batch + (SPLITK ? kh * 1024 : 0);
    const u16* B = g.B + g.strB * batch + (SPLITK ? kh * 1024 : 0);

    int m0, n0;
    if (XSW) {
        const int lid = blockIdx.y * gridDim.x + blockIdx.x;
        const int xcd = lid & 7;
        const int j   = lid >> 3;
        const int mper = gridDim.y >> 3;           // m-tiles per XCD stripe
        m0 = (xcd * mper + (j % mper)) * BM;
        n0 = (j / mper) * 128;
    } else {
        m0 = (MX ? blockIdx.x : blockIdx.y) * BM;
        n0 = (MX ? blockIdx.y : blockIdx.x) * 128;
    }

    const int t = threadIdx.x;
    const int w = t >> 6;
    const int lane = t & 63;
    const int quad = lane >> 4;
    const int l16  = lane & 15;
    const int wm = w >> 1, wn = w & 1;

    const int srow = w * 16 + (lane >> 2);
    const int skc  = (lane & 3) * 8;
    const u16* ga = A + (long)(m0 + srow) * g.lda + skc;
    const u16* gb = B + (long)(n0 + srow) * g.ldb + skc;
    const long a64 = (long)64 * g.lda;
    const long b64 = (long)64 * g.ldb;
    u16* lA = As + w * 512;
    u16* lB = Bs + w * 512;

    auto stage = [&](int buf, int k0) {
        u16* la = lA + buf * ASZ;
        u16* lb = lB + buf * BSZ;
        gload_lds16(ga + k0, la);
        if (TM == 4) gload_lds16(ga + a64 + k0, la + 2048);
        gload_lds16(gb + k0, lb);
        gload_lds16(gb + b64 + k0, lb + 2048);
    };

    f32x4 acc[TM][4] = {};
    const int K = SPLITK ? 1024 : g.K;

    stage(0, 0);
    int cur = 0;
    for (int k0 = 0; k0 < K; k0 += 32) {
        __syncthreads();
        if (k0 + 32 < K) stage(cur ^ 1, k0 + 32);

        const u16* as = As + cur * ASZ;
        const u16* bs = Bs + cur * BSZ;
        s16x8 af[TM], bf[4];
#pragma unroll
        for (int x = 0; x < TM; ++x)
            af[x] = *(const s16x8*)&as[(wm * (TM * 16) + x * 16 + l16) * 32 + quad * 8];
#pragma unroll
        for (int y = 0; y < 4; ++y)
            bf[y] = *(const s16x8*)&bs[(wn * 64 + y * 16 + l16) * 32 + quad * 8];
#pragma unroll
        for (int x = 0; x < TM; ++x)
#pragma unroll
            for (int y = 0; y < 4; ++y)
                acc[x][y] = __builtin_amdgcn_mfma_f32_16x16x32_bf16(af[x], bf[y], acc[x][y], 0, 0, 0);
        cur ^= 1;
    }

#pragma unroll
    for (int y = 0; y < 4; ++y) {
        const int col = n0 + wn * 64 + y * 16 + l16;
        float bval = 0.0f;
        if (CMODE == 2)
            bval = col < 512 ? g.bq[col] : (col < 1024 ? g.bk[col - 512] : g.bv[col - 1024]);
        else if (EPI >= 1)
            bval = g.bias[col];
#pragma unroll
        for (int x = 0; x < TM; ++x) {
#pragma unroll
            for (int r = 0; r < 4; ++r) {
                const int row = m0 + wm * (TM * 16) + x * 16 + quad * 4 + r;
                float v = acc[x][y][r] * g.scale + bval;
                if (EPI == 2) v = 0.5f * v * (1.0f + erff(v * 0.70710678118654752f));
                if (CMODE == 2) {
                    u16* dst = col < 512 ? g.qd : (col < 1024 ? g.kd : g.vd);
                    const int c = col & 511;
                    dst[(long)row * 512 + c] = f2bf(v);
                } else if (SPLITK) {
                    float* dst = kh ? g.Cpart : (float*)g.C;
                    dst[g.strC * batch + (long)row * g.ldc + col] = v;
                } else if (CMODE == 1) {
                    ((float*)g.C + g.strC * batch)[(long)row * g.ldc + col] = v;
                } else {
                    ((u16*)g.C + g.strC * batch)[(long)row * g.ldc + col] = f2bf(v);
                }
            }
        }
    }
}

// One block per score row; softmax in place over 2048 bf16 columns.
__launch_bounds__(256)
__global__ void softmax_k(u16* __restrict__ sc)
{
    const long base = (long)blockIdx.x * 2048;
    const int t = threadIdx.x;
    const int wid = t >> 6, lane = t & 63;
    __shared__ float redm[4];
    __shared__ float reds[4];

    float v[8];
    float mx = -1e30f;
#pragma unroll
    for (int i = 0; i < 8; ++i) {
        v[i] = bf2f(sc[base + i * 256 + t]);
        mx = fmaxf(mx, v[i]);
    }
#pragma unroll
    for (int off = 32; off; off >>= 1) mx = fmaxf(mx, __shfl_xor(mx, off, 64));
    if (lane == 0) redm[wid] = mx;
    __syncthreads();
    const float bm = fmaxf(fmaxf(redm[0], redm[1]), fmaxf(redm[2], redm[3]));

    float s = 0.0f;
#pragma unroll
    for (int i = 0; i < 8; ++i) { v[i] = expf(v[i] - bm); s += v[i]; }
#pragma unroll
    for (int off = 32; off; off >>= 1) s += __shfl_xor(s, off, 64);
    if (lane == 0) reds[wid] = s;
    __syncthreads();
    const float inv = 1.0f / (reds[0] + reds[1] + reds[2] + reds[3]);

#pragma unroll
    for (int i = 0; i < 8; ++i) sc[base + i * 256 + t] = f2bf(v[i] * inv);
}

// out[i] += part[i], f32x4 per thread. grid 4096.
__launch_bounds__(256)
__global__ void add_k(float* __restrict__ out, const float* __restrict__ part)
{
    const long i = ((long)blockIdx.x * 256 + threadIdx.x) * 4;
    f32x4 a = *(const f32x4*)(out + i);
    f32x4 b = *(const f32x4*)(part + i);
    a += b;
    *(f32x4*)(out + i) = a;
}

extern "C" void kernel_launch(void* const* d_in, const int* in_sizes, int n_in,
                              void* d_out, int out_size, void* d_ws, size_t ws_size,
                              hipStream_t stream)
{
    const int*   tok = (const int*)d_in[0];
    const float* emb = (const float*)d_in[1];
    const float* W1  = (const float*)d_in[2];
    const float* b1  = (const float*)d_in[3];
    const float* Wq  = (const float*)d_in[4];
    const float* bq  = (const float*)d_in[5];
    const float* Wk  = (const float*)d_in[6];
    const float* bk  = (const float*)d_in[7];
    const float* Wv  = (const float*)d_in[8];
    const float* bv  = (const float*)d_in[9];
    float* out = (float*)d_out;

    // d_out doubles as scratch until PV writes.
    u16* act   = (u16*)d_out;                  // [8192][512] bf16 (8 MiB)
    u16* wbase = act + 8192l * 512;
    u16* W1T = wbase;                          // [512][256]
    u16* WqT = wbase + 131072;                 // [1536][512] contiguous (q,k,v)
    u16* WkT = WqT + 262144;
    u16* WvT = WkT + 262144;

    char* ws = (char*)d_ws;
    u16* q    = (u16*)(ws);                    // [4][2048][512]
    u16* k    = (u16*)(ws + (8l  << 20));
    u16* vT   = (u16*)(ws + (16l << 20));      // [4][512][2048]
    u16* sc   = (u16*)(ws + (24l << 20));      // [4][2048][2048] bf16 (32 MiB)
    u16* embB = sc;                            // dead before sc written
    u16* vrow = sc;                            // v row-major [8192][512]; dead before sc
    float* wsP = (float*)ws;                   // 16 MiB partial, aliases q+k (dead by PV)

    const dim3 blk(256);
    const float iscl = 0.044194173824159216f;  // 1/sqrt(512)
    const long  TB = 2048l * 512;
    const long  SS = 2048l * 2048;

    // 0a. gathered embedding rows -> bf16 (XCD-striped to match GEMM1)
    cvt_gather_k<<<dim3(1024), blk, 0, stream>>>(emb, tok, embB);
    // 0b. weight transposes
    WArgs wa;
    wa.src[0] = W1; wa.src[1] = Wq; wa.src[2] = Wk; wa.src[3] = Wv;
    wa.dst[0] = W1T; wa.dst[1] = WqT; wa.dst[2] = WkT; wa.dst[3] = WvT;
    wa.K[0] = 256; wa.K[1] = 512; wa.K[2] = 512; wa.K[3] = 512;
    transpose_w_k<<<dim3(8, 8, 4), blk, 0, stream>>>(wa);

    // 1. act = gelu(embB @ W1T + b1)   M=8192 N=512 K=256, XCD-striped
    {
        GArgs a = {};
        a.A = embB; a.B = W1T; a.bias = b1; a.C = act;
        a.K = 256; a.lda = 256; a.ldb = 256; a.ldc = 512; a.scale = 1.0f;
        gemm128<2, 2, 0, false, false, true><<<dim3(4, 128, 1), blk, 0, stream>>>(a);
    }
    // 2. fused QKV (row-major q,k,v)   M=8192 N=1536 K=512, XCD-striped
    {
        GArgs a = {};
        a.A = act; a.B = WqT; a.K = 512; a.lda = 512; a.ldb = 512; a.scale = 1.0f;
        a.qd = q; a.kd = k; a.vd = vrow; a.bq = bq; a.bk = bk; a.bv = bv;
        gemm128<2, 0, 2, false, false, true><<<dim3(12, 128, 1), blk, 0, stream>>>(a);
    }
    // 2b. vT = transpose(v)
    transpose_v_k<<<dim3(8, 32, 4), blk, 0, stream>>>(vrow, vT);
    // 3. sc = q @ k^T / sqrt(512)   M=N=2048 K=512, z=batch
    {
        GArgs a = {};
        a.A = q; a.B = k; a.C = sc;
        a.K = 512; a.lda = 512; a.ldb = 512; a.ldc = 2048;
        a.strA = TB; a.strB = TB; a.strC = SS; a.scale = iscl;
        gemm128<4, 0, 0, false, false, false><<<dim3(16, 16, 4), blk, 0, stream>>>(a);
    }
    softmax_k<<<dim3(8192), blk, 0, stream>>>(sc);
    // 4. out = P @ vT^T  M=2048 N=512 K=2048, split-K x2, m-fastest
    {
        GArgs a = {};
        a.A = sc; a.B = vT; a.C = out; a.Cpart = wsP;
        a.K = 2048; a.lda = 2048; a.ldb = 2048; a.ldc = 512;
        a.strA = SS; a.strB = TB; a.strC = TB; a.scale = 1.0f;
        gemm128<2, 0, 1, true, true, false><<<dim3(32, 4, 8), blk, 0, stream>>>(a);
    }
    add_k<<<dim3(4096), blk, 0, stream>>>(out, wsP);
}

// Round 8
// 219.022 us; speedup vs baseline: 2.0997x; 1.0564x over previous
//
#include <hip/hip_runtime.h>
#include <math.h>

// ToyModel: B=4, S=2048, E=256, H=512, VOCAB=50257.
// Inputs/output f32; intermediates bf16; MFMA bf16 w/ f32 accum. posneg == identity.
//
// Round 8: wide-N tiles (BN=256) so the K-loop is MFMA-balanced:
//   TM=4/BN=256 (QK): 32 MFMA (~155cy) vs 12 ds_read_b128 (~144cy) per iter.
//   TM=2/BN=256 (QKV, PV): 16 MFMA vs 10 reads.
// GEMM1 stays TM=2/BN=128 (grid would collapse at BN=256). prep kernels merged.
//
// ws: q@0 | k@8MiB | vT@16MiB | sc@24MiB(32MiB) = 56 MiB (ws is 256 MiB).
// embB/vrow alias sc (dead before sc written); wsP aliases q+k (dead by PV).

typedef unsigned short u16;
typedef u16   u16x8 __attribute__((ext_vector_type(8)));
typedef short s16x8 __attribute__((ext_vector_type(8)));
typedef float f32x4 __attribute__((ext_vector_type(4)));
typedef float f32x8 __attribute__((ext_vector_type(8)));

static __device__ __forceinline__ u16 f2bf(float f) {
    unsigned u = __builtin_bit_cast(unsigned, f);
    u = (u + 0x7fffu + ((u >> 16) & 1u)) >> 16;   // RNE
    return (u16)u;
}
static __device__ __forceinline__ float bf2f(u16 h) {
    unsigned u = ((unsigned)h) << 16;
    return __builtin_bit_cast(float, u);
}

static __device__ __forceinline__ void gload_lds16(const u16* g, u16* l) {
    __builtin_amdgcn_global_load_lds(
        (const __attribute__((address_space(1))) void*)g,
        (__attribute__((address_space(3))) void*)l, 16, 0, 0);
}

struct PArgs {
    const float* wsrc[4];
    u16*         wdst[4];
    int          wK[4];
    const float* emb;
    const int*   tok;
    u16*         embB;
};

// z<4: f32 W[K][512] -> bf16 WT[512][K] (64x64 LDS transpose tiles).
// z>=4: gather+cvt embedding rows, XCD-striped to match GEMM1's stripes.
__launch_bounds__(256)
__global__ void prep_k(PArgs p)
{
    const int z = blockIdx.z;
    if (z < 4) {
        const float* W = p.wsrc[z];
        u16* WT = p.wdst[z];
        const int K = p.wK[z];
        const int c0 = blockIdx.x * 64;
        const int r0 = blockIdx.y * 64;
        if (r0 >= K) return;
        __shared__ float T[64][65];
        const int t = threadIdx.x;
        const int col = t & 63;
        const int rb  = t >> 6;
#pragma unroll
        for (int i = 0; i < 16; ++i)
            T[i * 4 + rb][col] = W[(long)(r0 + i * 4 + rb) * 512 + c0 + col];
        __syncthreads();
#pragma unroll
        for (int i = 0; i < 16; ++i) {
            const int orow = i * 4 + rb;
            WT[(long)(c0 + orow) * K + r0 + col] = f2bf(T[col][orow]);
        }
    } else {
        const int b = (z - 4) * 64 + blockIdx.y * 8 + blockIdx.x;   // 0..1023
        const int g = (b & 7) * 128 + (b >> 3);
        const int t = g * 2048 + threadIdx.x * 8;
        const int row = t >> 8;
        const int c8  = t & 255;
        f32x8 v = *(const f32x8*)(p.emb + (long)p.tok[row] * 256 + c8);
        u16x8 o;
#pragma unroll
        for (int j = 0; j < 8; ++j) o[j] = f2bf(v[j]);
        *(u16x8*)(p.embB + (long)row * 256 + c8) = o;
    }
}

// bf16 v[4*2048][512] -> vT[4][512][2048]. grid (8 h-tiles, 32 tok-tiles, 4).
__launch_bounds__(256)
__global__ void transpose_v_k(const u16* __restrict__ v, u16* __restrict__ vT)
{
    const int b  = blockIdx.z;
    const int h0 = blockIdx.x * 64;
    const int t0 = blockIdx.y * 64;
    __shared__ u16 T[64][65];
    const int t = threadIdx.x;
    const int col = t & 63;
    const int rb  = t >> 6;
#pragma unroll
    for (int i = 0; i < 16; ++i)
        T[i * 4 + rb][col] = v[(long)(b * 2048 + t0 + i * 4 + rb) * 512 + h0 + col];
    __syncthreads();
#pragma unroll
    for (int i = 0; i < 16; ++i) {
        const int orow = i * 4 + rb;
        vT[(long)b * (512 * 2048) + (long)(h0 + orow) * 2048 + t0 + col] = T[col][orow];
    }
}

struct GArgs {
    const u16* A; const u16* B; const float* bias; void* C;
    float* Cpart;
    u16 *qd, *kd, *vd;
    const float *bq, *bk, *bv;
    int K, lda, ldb, ldc;
    long strA, strB, strC;
    float scale;
};

// MFMA GEMM, dbuf async staging. BM=TM*32, BN=NT*32, BK=32. 4 waves 2x2:
// wave (wm,wn) covers TM m-tiles x NT n-tiles of 16x16.
// EPI: 0 scale, 1 +bias, 2 +bias+GELU.
// CMODE: 0 bf16 C, 1 f32 C, 2 QKV-fused (cols<512 q, <1024 k, else v; row-major).
// MX: m-tile fastest. SPLITK: z=batch*2+kh, K half = 1024. XSW: XCD m-stripes.
template <int TM, int NT, int EPI, int CMODE, bool MX, bool SPLITK, bool XSW>
__launch_bounds__(256, 2)
__global__ void gemm128(GArgs g)
{
    constexpr int BM  = TM * 32;
    constexpr int BN  = NT * 32;
    constexpr int ASZ = BM * 32;
    constexpr int BSZ = BN * 32;
    __shared__ u16 As[2 * ASZ];
    __shared__ u16 Bs[2 * BSZ];

    const int bz    = blockIdx.z;
    const int batch = SPLITK ? (bz >> 1) : bz;
    const int kh    = SPLITK ? (bz & 1) : 0;
    const u16* A = g.A + g.strA * batch + (SPLITK ? kh * 1024 : 0);
    const u16* B = g.B + g.strB * batch + (SPLITK ? kh * 1024 : 0);

    int m0, n0;
    if (XSW) {
        const int lid = blockIdx.y * gridDim.x + blockIdx.x;
        const int xcd = lid & 7;
        const int j   = lid >> 3;
        const int mper = gridDim.y >> 3;
        m0 = (xcd * mper + (j % mper)) * BM;
        n0 = (j / mper) * BN;
    } else {
        m0 = (MX ? blockIdx.x : blockIdx.y) * BM;
        n0 = (MX ? blockIdx.y : blockIdx.x) * BN;
    }

    const int t = threadIdx.x;
    const int w = t >> 6;
    const int lane = t & 63;
    const int quad = lane >> 4;
    const int l16  = lane & 15;
    const int wm = w >> 1, wn = w & 1;

    const int srow = w * 16 + (lane >> 2);
    const int skc  = (lane & 3) * 8;
    const u16* ga = A + (long)(m0 + srow) * g.lda + skc;
    const u16* gb = B + (long)(n0 + srow) * g.ldb + skc;
    const long a64 = (long)64 * g.lda;
    const long b64 = (long)64 * g.ldb;
    u16* lA = As + w * 512;
    u16* lB = Bs + w * 512;

    auto stage = [&](int buf, int k0) {
        u16* la = lA + buf * ASZ;
        u16* lb = lB + buf * BSZ;
#pragma unroll
        for (int i = 0; i < TM / 2; ++i) gload_lds16(ga + i * a64 + k0, la + i * 2048);
#pragma unroll
        for (int i = 0; i < NT / 2; ++i) gload_lds16(gb + i * b64 + k0, lb + i * 2048);
    };

    f32x4 acc[TM][NT] = {};
    const int K = SPLITK ? 1024 : g.K;

    stage(0, 0);
    int cur = 0;
    for (int k0 = 0; k0 < K; k0 += 32) {
        __syncthreads();
        if (k0 + 32 < K) stage(cur ^ 1, k0 + 32);

        const u16* as = As + cur * ASZ;
        const u16* bs = Bs + cur * BSZ;
        s16x8 af[TM], bf[NT];
#pragma unroll
        for (int x = 0; x < TM; ++x)
            af[x] = *(const s16x8*)&as[(wm * (TM * 16) + x * 16 + l16) * 32 + quad * 8];
#pragma unroll
        for (int y = 0; y < NT; ++y)
            bf[y] = *(const s16x8*)&bs[(wn * (NT * 16) + y * 16 + l16) * 32 + quad * 8];
#pragma unroll
        for (int x = 0; x < TM; ++x)
#pragma unroll
            for (int y = 0; y < NT; ++y)
                acc[x][y] = __builtin_amdgcn_mfma_f32_16x16x32_bf16(af[x], bf[y], acc[x][y], 0, 0, 0);
        cur ^= 1;
    }

#pragma unroll
    for (int y = 0; y < NT; ++y) {
        const int col = n0 + wn * (NT * 16) + y * 16 + l16;
        float bval = 0.0f;
        if (CMODE == 2)
            bval = col < 512 ? g.bq[col] : (col < 1024 ? g.bk[col - 512] : g.bv[col - 1024]);
        else if (EPI >= 1)
            bval = g.bias[col];
#pragma unroll
        for (int x = 0; x < TM; ++x) {
#pragma unroll
            for (int r = 0; r < 4; ++r) {
                const int row = m0 + wm * (TM * 16) + x * 16 + quad * 4 + r;
                float v = acc[x][y][r] * g.scale + bval;
                if (EPI == 2) v = 0.5f * v * (1.0f + erff(v * 0.70710678118654752f));
                if (CMODE == 2) {
                    u16* dst = col < 512 ? g.qd : (col < 1024 ? g.kd : g.vd);
                    dst[(long)row * 512 + (col & 511)] = f2bf(v);
                } else if (SPLITK) {
                    float* dst = kh ? g.Cpart : (float*)g.C;
                    dst[g.strC * batch + (long)row * g.ldc + col] = v;
                } else if (CMODE == 1) {
                    ((float*)g.C + g.strC * batch)[(long)row * g.ldc + col] = v;
                } else {
                    ((u16*)g.C + g.strC * batch)[(long)row * g.ldc + col] = f2bf(v);
                }
            }
        }
    }
}

// One block per score row; softmax in place over 2048 bf16 columns.
__launch_bounds__(256)
__global__ void softmax_k(u16* __restrict__ sc)
{
    const long base = (long)blockIdx.x * 2048;
    const int t = threadIdx.x;
    const int wid = t >> 6, lane = t & 63;
    __shared__ float redm[4];
    __shared__ float reds[4];

    float v[8];
    float mx = -1e30f;
#pragma unroll
    for (int i = 0; i < 8; ++i) {
        v[i] = bf2f(sc[base + i * 256 + t]);
        mx = fmaxf(mx, v[i]);
    }
#pragma unroll
    for (int off = 32; off; off >>= 1) mx = fmaxf(mx, __shfl_xor(mx, off, 64));
    if (lane == 0) redm[wid] = mx;
    __syncthreads();
    const float bm = fmaxf(fmaxf(redm[0], redm[1]), fmaxf(redm[2], redm[3]));

    float s = 0.0f;
#pragma unroll
    for (int i = 0; i < 8; ++i) { v[i] = __expf(v[i] - bm); s += v[i]; }
#pragma unroll
    for (int off = 32; off; off >>= 1) s += __shfl_xor(s, off, 64);
    if (lane == 0) reds[wid] = s;
    __syncthreads();
    const float inv = 1.0f / (reds[0] + reds[1] + reds[2] + reds[3]);

#pragma unroll
    for (int i = 0; i < 8; ++i) sc[base + i * 256 + t] = f2bf(v[i] * inv);
}

// out[i] += part[i], f32x4 per thread. grid 4096.
__launch_bounds__(256)
__global__ void add_k(float* __restrict__ out, const float* __restrict__ part)
{
    const long i = ((long)blockIdx.x * 256 + threadIdx.x) * 4;
    f32x4 a = *(const f32x4*)(out + i);
    f32x4 b = *(const f32x4*)(part + i);
    a += b;
    *(f32x4*)(out + i) = a;
}

extern "C" void kernel_launch(void* const* d_in, const int* in_sizes, int n_in,
                              void* d_out, int out_size, void* d_ws, size_t ws_size,
                              hipStream_t stream)
{
    const int*   tok = (const int*)d_in[0];
    const float* emb = (const float*)d_in[1];
    const float* W1  = (const float*)d_in[2];
    const float* b1  = (const float*)d_in[3];
    const float* Wq  = (const float*)d_in[4];
    const float* bq  = (const float*)d_in[5];
    const float* Wk  = (const float*)d_in[6];
    const float* bk  = (const float*)d_in[7];
    const float* Wv  = (const float*)d_in[8];
    const float* bv  = (const float*)d_in[9];
    float* out = (float*)d_out;

    u16* act   = (u16*)d_out;                  // [8192][512] bf16 (8 MiB)
    u16* wbase = act + 8192l * 512;
    u16* W1T = wbase;                          // [512][256]
    u16* WqT = wbase + 131072;                 // [1536][512] contiguous
    u16* WkT = WqT + 262144;
    u16* WvT = WkT + 262144;

    char* ws = (char*)d_ws;
    u16* q    = (u16*)(ws);
    u16* k    = (u16*)(ws + (8l  << 20));
    u16* vT   = (u16*)(ws + (16l << 20));
    u16* sc   = (u16*)(ws + (24l << 20));
    u16* embB = sc;                            // dead before sc written
    u16* vrow = sc;                            // dead before sc written
    float* wsP = (float*)ws;                   // aliases q+k (dead by PV)

    const dim3 blk(256);
    const float iscl = 0.044194173824159216f;  // 1/sqrt(512)
    const long  TB = 2048l * 512;
    const long  SS = 2048l * 2048;

    // 0. prep: weight transposes (z<4) + XCD-striped gather+cvt (z>=4)
    PArgs p;
    p.wsrc[0] = W1; p.wsrc[1] = Wq; p.wsrc[2] = Wk; p.wsrc[3] = Wv;
    p.wdst[0] = W1T; p.wdst[1] = WqT; p.wdst[2] = WkT; p.wdst[3] = WvT;
    p.wK[0] = 256; p.wK[1] = 512; p.wK[2] = 512; p.wK[3] = 512;
    p.emb = emb; p.tok = tok; p.embB = embB;
    prep_k<<<dim3(8, 8, 20), blk, 0, stream>>>(p);

    // 1. act = gelu(embB @ W1T + b1)   M=8192 N=512 K=256  TM=2 BN=128 XSW
    {
        GArgs a = {};
        a.A = embB; a.B = W1T; a.bias = b1; a.C = act;
        a.K = 256; a.lda = 256; a.ldb = 256; a.ldc = 512; a.scale = 1.0f;
        gemm128<2, 4, 2, 0, false, false, true><<<dim3(4, 128, 1), blk, 0, stream>>>(a);
    }
    // 2. fused QKV   M=8192 N=1536 K=512  TM=2 BN=256 XSW (768 blocks)
    {
        GArgs a = {};
        a.A = act; a.B = WqT; a.K = 512; a.lda = 512; a.ldb = 512; a.scale = 1.0f;
        a.qd = q; a.kd = k; a.vd = vrow; a.bq = bq; a.bk = bk; a.bv = bv;
        gemm128<2, 8, 0, 2, false, false, true><<<dim3(6, 128, 1), blk, 0, stream>>>(a);
    }
    // 2b. vT = transpose(v)
    transpose_v_k<<<dim3(8, 32, 4), blk, 0, stream>>>(vrow, vT);
    // 3. sc = q @ k^T / sqrt(512)   M=N=2048 K=512  TM=4 BN=256 (512 blocks)
    {
        GArgs a = {};
        a.A = q; a.B = k; a.C = sc;
        a.K = 512; a.lda = 512; a.ldb = 512; a.ldc = 2048;
        a.strA = TB; a.strB = TB; a.strC = SS; a.scale = iscl;
        gemm128<4, 8, 0, 0, false, false, false><<<dim3(8, 16, 4), blk, 0, stream>>>(a);
    }
    softmax_k<<<dim3(8192), blk, 0, stream>>>(sc);
    // 4. out = P @ vT^T   M=2048 N=512 K=2048  TM=2 BN=256, split-K x2, MX (512 blocks)
    {
        GArgs a = {};
        a.A = sc; a.B = vT; a.C = out; a.Cpart = wsP;
        a.K = 2048; a.lda = 2048; a.ldb = 2048; a.ldc = 512;
        a.strA = SS; a.strB = TB; a.strC = TB; a.scale = 1.0f;
        gemm128<2, 8, 0, 1, true, true, false><<<dim3(32, 2, 8), blk, 0, stream>>>(a);
    }
    add_k<<<dim3(4096), blk, 0, stream>>>(out, wsP);
}

// Round 9
// 211.065 us; speedup vs baseline: 2.1789x; 1.0377x over previous
//
#include <hip/hip_runtime.h>
#include <math.h>

// ToyModel: B=4, S=2048, E=256, H=512, VOCAB=50257.
// Inputs/output f32; intermediates bf16; MFMA bf16 w/ f32 accum. posneg == identity.
//
// Round 9: softmax kernel eliminated. QK epilogue emits e=exp(s/sqrt(512))
// (no max-subtract: scores bounded ~+-1.5) + per-row partial sums lsum[16][8192]
// (non-atomic, each slot written once). PV sums raw e*v; add_k applies the
// split-K merge AND the 1/l row normalizer.
//
// ws: q@0 | k@8MiB | vT@16MiB | sc@24MiB(32MiB) | lsum@56MiB(512KB).
// embB/vrow alias sc (dead before sc written); wsP aliases q+k (dead by PV).

typedef unsigned short u16;
typedef u16   u16x8 __attribute__((ext_vector_type(8)));
typedef short s16x8 __attribute__((ext_vector_type(8)));
typedef float f32x4 __attribute__((ext_vector_type(4)));
typedef float f32x8 __attribute__((ext_vector_type(8)));

static __device__ __forceinline__ u16 f2bf(float f) {
    unsigned u = __builtin_bit_cast(unsigned, f);
    u = (u + 0x7fffu + ((u >> 16) & 1u)) >> 16;   // RNE
    return (u16)u;
}

static __device__ __forceinline__ void gload_lds16(const u16* g, u16* l) {
    __builtin_amdgcn_global_load_lds(
        (const __attribute__((address_space(1))) void*)g,
        (__attribute__((address_space(3))) void*)l, 16, 0, 0);
}

struct PArgs {
    const float* wsrc[4];
    u16*         wdst[4];
    int          wK[4];
    const float* emb;
    const int*   tok;
    u16*         embB;
};

// z<4: f32 W[K][512] -> bf16 WT[512][K]. z>=4: XCD-striped gather+cvt of emb rows.
__launch_bounds__(256)
__global__ void prep_k(PArgs p)
{
    const int z = blockIdx.z;
    if (z < 4) {
        const float* W = p.wsrc[z];
        u16* WT = p.wdst[z];
        const int K = p.wK[z];
        const int c0 = blockIdx.x * 64;
        const int r0 = blockIdx.y * 64;
        if (r0 >= K) return;
        __shared__ float T[64][65];
        const int t = threadIdx.x;
        const int col = t & 63;
        const int rb  = t >> 6;
#pragma unroll
        for (int i = 0; i < 16; ++i)
            T[i * 4 + rb][col] = W[(long)(r0 + i * 4 + rb) * 512 + c0 + col];
        __syncthreads();
#pragma unroll
        for (int i = 0; i < 16; ++i) {
            const int orow = i * 4 + rb;
            WT[(long)(c0 + orow) * K + r0 + col] = f2bf(T[col][orow]);
        }
    } else {
        const int b = (z - 4) * 64 + blockIdx.y * 8 + blockIdx.x;   // 0..1023
        const int g = (b & 7) * 128 + (b >> 3);
        const int t = g * 2048 + threadIdx.x * 8;
        const int row = t >> 8;
        const int c8  = t & 255;
        f32x8 v = *(const f32x8*)(p.emb + (long)p.tok[row] * 256 + c8);
        u16x8 o;
#pragma unroll
        for (int j = 0; j < 8; ++j) o[j] = f2bf(v[j]);
        *(u16x8*)(p.embB + (long)row * 256 + c8) = o;
    }
}

// bf16 v[4*2048][512] -> vT[4][512][2048]. grid (8 h-tiles, 32 tok-tiles, 4).
__launch_bounds__(256)
__global__ void transpose_v_k(const u16* __restrict__ v, u16* __restrict__ vT)
{
    const int b  = blockIdx.z;
    const int h0 = blockIdx.x * 64;
    const int t0 = blockIdx.y * 64;
    __shared__ u16 T[64][65];
    const int t = threadIdx.x;
    const int col = t & 63;
    const int rb  = t >> 6;
#pragma unroll
    for (int i = 0; i < 16; ++i)
        T[i * 4 + rb][col] = v[(long)(b * 2048 + t0 + i * 4 + rb) * 512 + h0 + col];
    __syncthreads();
#pragma unroll
    for (int i = 0; i < 16; ++i) {
        const int orow = i * 4 + rb;
        vT[(long)b * (512 * 2048) + (long)(h0 + orow) * 2048 + t0 + col] = T[col][orow];
    }
}

struct GArgs {
    const u16* A; const u16* B; const float* bias; void* C;
    float* Cpart;
    float* lsum;                          // [16][8192] QK row partial sums
    u16 *qd, *kd, *vd;
    const float *bq, *bk, *bv;
    int K, lda, ldb, ldc;
    long strA, strB, strC;
    float scale;
};

// MFMA GEMM, dbuf async staging. BM=TM*32, BN=NT*32, BK=32. 4 waves 2x2.
// EPI: 0 scale, 1 +bias, 2 +bias+GELU.
// CMODE: 0 bf16 C, 1 f32 C, 2 QKV-fused, 3 QK+exp (store e=exp(acc*scale) bf16,
//        per-row partial sums -> lsum[2*bx+wn][batch*2048+row], no atomics).
// MX: m-tile fastest. SPLITK: z=batch*2+kh, K half = 1024. XSW: XCD m-stripes.
template <int TM, int NT, int EPI, int CMODE, bool MX, bool SPLITK, bool XSW>
__launch_bounds__(256, 2)
__global__ void gemm128(GArgs g)
{
    constexpr int BM  = TM * 32;
    constexpr int BN  = NT * 32;
    constexpr int ASZ = BM * 32;
    constexpr int BSZ = BN * 32;
    __shared__ u16 As[2 * ASZ];
    __shared__ u16 Bs[2 * BSZ];

    const int bz    = blockIdx.z;
    const int batch = SPLITK ? (bz >> 1) : bz;
    const int kh    = SPLITK ? (bz & 1) : 0;
    const u16* A = g.A + g.strA * batch + (SPLITK ? kh * 1024 : 0);
    const u16* B = g.B + g.strB * batch + (SPLITK ? kh * 1024 : 0);

    int m0, n0;
    if (XSW) {
        const int lid = blockIdx.y * gridDim.x + blockIdx.x;
        const int xcd = lid & 7;
        const int j   = lid >> 3;
        const int mper = gridDim.y >> 3;
        m0 = (xcd * mper + (j % mper)) * BM;
        n0 = (j / mper) * BN;
    } else {
        m0 = (MX ? blockIdx.x : blockIdx.y) * BM;
        n0 = (MX ? blockIdx.y : blockIdx.x) * BN;
    }

    const int t = threadIdx.x;
    const int w = t >> 6;
    const int lane = t & 63;
    const int quad = lane >> 4;
    const int l16  = lane & 15;
    const int wm = w >> 1, wn = w & 1;

    const int srow = w * 16 + (lane >> 2);
    const int skc  = (lane & 3) * 8;
    const u16* ga = A + (long)(m0 + srow) * g.lda + skc;
    const u16* gb = B + (long)(n0 + srow) * g.ldb + skc;
    const long a64 = (long)64 * g.lda;
    const long b64 = (long)64 * g.ldb;
    u16* lA = As + w * 512;
    u16* lB = Bs + w * 512;

    auto stage = [&](int buf, int k0) {
        u16* la = lA + buf * ASZ;
        u16* lb = lB + buf * BSZ;
#pragma unroll
        for (int i = 0; i < TM / 2; ++i) gload_lds16(ga + i * a64 + k0, la + i * 2048);
#pragma unroll
        for (int i = 0; i < NT / 2; ++i) gload_lds16(gb + i * b64 + k0, lb + i * 2048);
    };

    f32x4 acc[TM][NT] = {};
    const int K = SPLITK ? 1024 : g.K;

    stage(0, 0);
    int cur = 0;
    for (int k0 = 0; k0 < K; k0 += 32) {
        __syncthreads();
        if (k0 + 32 < K) stage(cur ^ 1, k0 + 32);

        const u16* as = As + cur * ASZ;
        const u16* bs = Bs + cur * BSZ;
        s16x8 af[TM], bf[NT];
#pragma unroll
        for (int x = 0; x < TM; ++x)
            af[x] = *(const s16x8*)&as[(wm * (TM * 16) + x * 16 + l16) * 32 + quad * 8];
#pragma unroll
        for (int y = 0; y < NT; ++y)
            bf[y] = *(const s16x8*)&bs[(wn * (NT * 16) + y * 16 + l16) * 32 + quad * 8];
#pragma unroll
        for (int x = 0; x < TM; ++x)
#pragma unroll
            for (int y = 0; y < NT; ++y)
                acc[x][y] = __builtin_amdgcn_mfma_f32_16x16x32_bf16(af[x], bf[y], acc[x][y], 0, 0, 0);
        cur ^= 1;
    }

    float rs[TM][4];
    if (CMODE == 3)
#pragma unroll
        for (int x = 0; x < TM; ++x)
#pragma unroll
            for (int r = 0; r < 4; ++r) rs[x][r] = 0.0f;

#pragma unroll
    for (int y = 0; y < NT; ++y) {
        const int col = n0 + wn * (NT * 16) + y * 16 + l16;
        float bval = 0.0f;
        if (CMODE == 2)
            bval = col < 512 ? g.bq[col] : (col < 1024 ? g.bk[col - 512] : g.bv[col - 1024]);
        else if (EPI >= 1)
            bval = g.bias[col];
#pragma unroll
        for (int x = 0; x < TM; ++x) {
#pragma unroll
            for (int r = 0; r < 4; ++r) {
                const int row = m0 + wm * (TM * 16) + x * 16 + quad * 4 + r;
                float v = acc[x][y][r] * g.scale + bval;
                if (EPI == 2) v = 0.5f * v * (1.0f + erff(v * 0.70710678118654752f));
                if (CMODE == 3) {
                    const float e = __expf(v);
                    rs[x][r] += e;
                    ((u16*)g.C + g.strC * batch)[(long)row * g.ldc + col] = f2bf(e);
                } else if (CMODE == 2) {
                    u16* dst = col < 512 ? g.qd : (col < 1024 ? g.kd : g.vd);
                    dst[(long)row * 512 + (col & 511)] = f2bf(v);
                } else if (SPLITK) {
                    float* dst = kh ? g.Cpart : (float*)g.C;
                    dst[g.strC * batch + (long)row * g.ldc + col] = v;
                } else if (CMODE == 1) {
                    ((float*)g.C + g.strC * batch)[(long)row * g.ldc + col] = v;
                } else {
                    ((u16*)g.C + g.strC * batch)[(long)row * g.ldc + col] = f2bf(v);
                }
            }
        }
    }

    if (CMODE == 3) {
        // per-row sums: reduce the 16 l16 lanes (same quad), lane l16==0 stores.
#pragma unroll
        for (int x = 0; x < TM; ++x) {
#pragma unroll
            for (int r = 0; r < 4; ++r) {
                float s = rs[x][r];
                s += __shfl_xor(s, 1, 64);
                s += __shfl_xor(s, 2, 64);
                s += __shfl_xor(s, 4, 64);
                s += __shfl_xor(s, 8, 64);
                if (l16 == 0) {
                    const int row = m0 + wm * (TM * 16) + x * 16 + quad * 4 + r;
                    g.lsum[(long)(2 * blockIdx.x + wn) * 8192 + batch * 2048 + row] = s;
                }
            }
        }
    }
}

// out[i] = (out[i] + part[i]) / l[row].  4 f32 per thread, 4096 blocks.
__launch_bounds__(256)
__global__ void add_k(float* __restrict__ out, const float* __restrict__ part,
                      const float* __restrict__ lsum)
{
    const long i = ((long)blockIdx.x * 256 + threadIdx.x) * 4;
    const int row = (int)(i >> 9);                 // 512 f32 per row
    float l = 0.0f;
#pragma unroll
    for (int j = 0; j < 16; ++j) l += lsum[(long)j * 8192 + row];
    const float inv = 1.0f / l;
    f32x4 a = *(const f32x4*)(out + i);
    f32x4 b = *(const f32x4*)(part + i);
    a = (a + b) * inv;
    *(f32x4*)(out + i) = a;
}

extern "C" void kernel_launch(void* const* d_in, const int* in_sizes, int n_in,
                              void* d_out, int out_size, void* d_ws, size_t ws_size,
                              hipStream_t stream)
{
    const int*   tok = (const int*)d_in[0];
    const float* emb = (const float*)d_in[1];
    const float* W1  = (const float*)d_in[2];
    const float* b1  = (const float*)d_in[3];
    const float* Wq  = (const float*)d_in[4];
    const float* bq  = (const float*)d_in[5];
    const float* Wk  = (const float*)d_in[6];
    const float* bk  = (const float*)d_in[7];
    const float* Wv  = (const float*)d_in[8];
    const float* bv  = (const float*)d_in[9];
    float* out = (float*)d_out;

    u16* act   = (u16*)d_out;                  // [8192][512] bf16 (8 MiB)
    u16* wbase = act + 8192l * 512;
    u16* W1T = wbase;                          // [512][256]
    u16* WqT = wbase + 131072;                 // [1536][512] contiguous
    u16* WkT = WqT + 262144;
    u16* WvT = WkT + 262144;

    char* ws = (char*)d_ws;
    u16* q     = (u16*)(ws);
    u16* k     = (u16*)(ws + (8l  << 20));
    u16* vT    = (u16*)(ws + (16l << 20));
    u16* sc    = (u16*)(ws + (24l << 20));     // 32 MiB (e values)
    float* lsum = (float*)(ws + (56l << 20));  // [16][8192] f32
    u16* embB  = sc;                           // dead before sc written
    u16* vrow  = sc;                           // dead before sc written
    float* wsP = (float*)ws;                   // aliases q+k (dead by PV)

    const dim3 blk(256);
    const float iscl = 0.044194173824159216f;  // 1/sqrt(512)
    const long  TB = 2048l * 512;
    const long  SS = 2048l * 2048;

    // 0. prep: weight transposes (z<4) + XCD-striped gather+cvt (z>=4)
    PArgs p;
    p.wsrc[0] = W1; p.wsrc[1] = Wq; p.wsrc[2] = Wk; p.wsrc[3] = Wv;
    p.wdst[0] = W1T; p.wdst[1] = WqT; p.wdst[2] = WkT; p.wdst[3] = WvT;
    p.wK[0] = 256; p.wK[1] = 512; p.wK[2] = 512; p.wK[3] = 512;
    p.emb = emb; p.tok = tok; p.embB = embB;
    prep_k<<<dim3(8, 8, 20), blk, 0, stream>>>(p);

    // 1. act = gelu(embB @ W1T + b1)   M=8192 N=512 K=256  TM=2 BN=128 XSW
    {
        GArgs a = {};
        a.A = embB; a.B = W1T; a.bias = b1; a.C = act;
        a.K = 256; a.lda = 256; a.ldb = 256; a.ldc = 512; a.scale = 1.0f;
        gemm128<2, 4, 2, 0, false, false, true><<<dim3(4, 128, 1), blk, 0, stream>>>(a);
    }
    // 2. fused QKV   M=8192 N=1536 K=512  TM=2 BN=256 XSW (768 blocks)
    {
        GArgs a = {};
        a.A = act; a.B = WqT; a.K = 512; a.lda = 512; a.ldb = 512; a.scale = 1.0f;
        a.qd = q; a.kd = k; a.vd = vrow; a.bq = bq; a.bk = bk; a.bv = bv;
        gemm128<2, 8, 0, 2, false, false, true><<<dim3(6, 128, 1), blk, 0, stream>>>(a);
    }
    // 2b. vT = transpose(v)
    transpose_v_k<<<dim3(8, 32, 4), blk, 0, stream>>>(vrow, vT);
    // 3. e = exp(q @ k^T / sqrt(512)) + row sums   M=N=2048 K=512  TM=4 BN=256
    {
        GArgs a = {};
        a.A = q; a.B = k; a.C = sc; a.lsum = lsum;
        a.K = 512; a.lda = 512; a.ldb = 512; a.ldc = 2048;
        a.strA = TB; a.strB = TB; a.strC = SS; a.scale = iscl;
        gemm128<4, 8, 0, 3, false, false, false><<<dim3(8, 16, 4), blk, 0, stream>>>(a);
    }
    // 4. raw = e @ vT^T   M=2048 N=512 K=2048  TM=2 BN=256, split-K x2, MX
    {
        GArgs a = {};
        a.A = sc; a.B = vT; a.C = out; a.Cpart = wsP;
        a.K = 2048; a.lda = 2048; a.ldb = 2048; a.ldc = 512;
        a.strA = SS; a.strB = TB; a.strC = TB; a.scale = 1.0f;
        gemm128<2, 8, 0, 1, true, true, false><<<dim3(32, 2, 8), blk, 0, stream>>>(a);
    }
    // 5. out = (kh0 + kh1) / l_row
    add_k<<<dim3(4096), blk, 0, stream>>>(out, wsP, lsum);
}

// Round 10
// 201.057 us; speedup vs baseline: 2.2874x; 1.0498x over previous
//
#include <hip/hip_runtime.h>
#include <math.h>

// ToyModel: B=4, S=2048, E=256, H=512, VOCAB=50257.
// Inputs/output f32; intermediates bf16; MFMA bf16 w/ f32 accum. posneg == identity.
//
// Round 10: transpose_v eliminated — QKV's v-blocks (n0>=1024) repack their
// C-tile through LDS ([col][m], pad 72 for alignment+banks) and store vT in
// 128-B runs (2 full cache lines per col). Rest identical to round 9:
// QK+exp epilogue + lsum partials, split-K PV, add_k merge+normalize.
//
// ws: q@0 | k@8MiB | vT@16MiB | sc@24MiB(32MiB) | lsum@56MiB(512KB).
// embB aliases sc (dead before sc written); wsP aliases q+k (dead by PV).

typedef unsigned short u16;
typedef u16   u16x8 __attribute__((ext_vector_type(8)));
typedef short s16x8 __attribute__((ext_vector_type(8)));
typedef float f32x4 __attribute__((ext_vector_type(4)));
typedef float f32x8 __attribute__((ext_vector_type(8)));

static __device__ __forceinline__ u16 f2bf(float f) {
    unsigned u = __builtin_bit_cast(unsigned, f);
    u = (u + 0x7fffu + ((u >> 16) & 1u)) >> 16;   // RNE
    return (u16)u;
}

static __device__ __forceinline__ void gload_lds16(const u16* g, u16* l) {
    __builtin_amdgcn_global_load_lds(
        (const __attribute__((address_space(1))) void*)g,
        (__attribute__((address_space(3))) void*)l, 16, 0, 0);
}

struct PArgs {
    const float* wsrc[4];
    u16*         wdst[4];
    int          wK[4];
    const float* emb;
    const int*   tok;
    u16*         embB;
};

// z<4: f32 W[K][512] -> bf16 WT[512][K]. z>=4: XCD-striped gather+cvt of emb rows.
__launch_bounds__(256)
__global__ void prep_k(PArgs p)
{
    const int z = blockIdx.z;
    if (z < 4) {
        const float* W = p.wsrc[z];
        u16* WT = p.wdst[z];
        const int K = p.wK[z];
        const int c0 = blockIdx.x * 64;
        const int r0 = blockIdx.y * 64;
        if (r0 >= K) return;
        __shared__ float T[64][65];
        const int t = threadIdx.x;
        const int col = t & 63;
        const int rb  = t >> 6;
#pragma unroll
        for (int i = 0; i < 16; ++i)
            T[i * 4 + rb][col] = W[(long)(r0 + i * 4 + rb) * 512 + c0 + col];
        __syncthreads();
#pragma unroll
        for (int i = 0; i < 16; ++i) {
            const int orow = i * 4 + rb;
            WT[(long)(c0 + orow) * K + r0 + col] = f2bf(T[col][orow]);
        }
    } else {
        const int b = (z - 4) * 64 + blockIdx.y * 8 + blockIdx.x;   // 0..1023
        const int g = (b & 7) * 128 + (b >> 3);
        const int t = g * 2048 + threadIdx.x * 8;
        const int row = t >> 8;
        const int c8  = t & 255;
        f32x8 v = *(const f32x8*)(p.emb + (long)p.tok[row] * 256 + c8);
        u16x8 o;
#pragma unroll
        for (int j = 0; j < 8; ++j) o[j] = f2bf(v[j]);
        *(u16x8*)(p.embB + (long)row * 256 + c8) = o;
    }
}

struct GArgs {
    const u16* A; const u16* B; const float* bias; void* C;
    float* Cpart;
    float* lsum;                          // [16][8192] QK row partial sums
    u16 *qd, *kd, *vTd;
    const float *bq, *bk, *bv;
    int K, lda, ldb, ldc;
    long strA, strB, strC;
    float scale;
};

// MFMA GEMM, dbuf async staging. BM=TM*32, BN=NT*32, BK=32. 4 waves 2x2.
// EPI: 0 scale, 1 +bias, 2 +bias+GELU.
// CMODE: 0 bf16 C, 1 f32 C, 2 QKV-fused (n0<1024: q/k row-major; n0>=1024:
//        v repacked via LDS -> vT[batch][h][pos] in 128-B runs), 3 QK+exp.
// MX: m-tile fastest. SPLITK: z=batch*2+kh, K half = 1024. XSW: XCD m-stripes.
template <int TM, int NT, int EPI, int CMODE, bool MX, bool SPLITK, bool XSW>
__launch_bounds__(256, 2)
__global__ void gemm128(GArgs g)
{
    constexpr int BM  = TM * 32;
    constexpr int BN  = NT * 32;
    constexpr int ASZ = BM * 32;
    constexpr int BSZ = BN * 32;
    __shared__ u16 smem[2 * (ASZ + BSZ)];
    u16* As = smem;
    u16* Bs = smem + 2 * ASZ;

    const int bz    = blockIdx.z;
    const int batch = SPLITK ? (bz >> 1) : bz;
    const int kh    = SPLITK ? (bz & 1) : 0;
    const u16* A = g.A + g.strA * batch + (SPLITK ? kh * 1024 : 0);
    const u16* B = g.B + g.strB * batch + (SPLITK ? kh * 1024 : 0);

    int m0, n0;
    if (XSW) {
        const int lid = blockIdx.y * gridDim.x + blockIdx.x;
        const int xcd = lid & 7;
        const int j   = lid >> 3;
        const int mper = gridDim.y >> 3;
        m0 = (xcd * mper + (j % mper)) * BM;
        n0 = (j / mper) * BN;
    } else {
        m0 = (MX ? blockIdx.x : blockIdx.y) * BM;
        n0 = (MX ? blockIdx.y : blockIdx.x) * BN;
    }

    const int t = threadIdx.x;
    const int w = t >> 6;
    const int lane = t & 63;
    const int quad = lane >> 4;
    const int l16  = lane & 15;
    const int wm = w >> 1, wn = w & 1;

    const int srow = w * 16 + (lane >> 2);
    const int skc  = (lane & 3) * 8;
    const u16* ga = A + (long)(m0 + srow) * g.lda + skc;
    const u16* gb = B + (long)(n0 + srow) * g.ldb + skc;
    const long a64 = (long)64 * g.lda;
    const long b64 = (long)64 * g.ldb;
    u16* lA = As + w * 512;
    u16* lB = Bs + w * 512;

    auto stage = [&](int buf, int k0) {
        u16* la = lA + buf * ASZ;
        u16* lb = lB + buf * BSZ;
#pragma unroll
        for (int i = 0; i < TM / 2; ++i) gload_lds16(ga + i * a64 + k0, la + i * 2048);
#pragma unroll
        for (int i = 0; i < NT / 2; ++i) gload_lds16(gb + i * b64 + k0, lb + i * 2048);
    };

    f32x4 acc[TM][NT] = {};
    const int K = SPLITK ? 1024 : g.K;

    stage(0, 0);
    int cur = 0;
    for (int k0 = 0; k0 < K; k0 += 32) {
        __syncthreads();
        if (k0 + 32 < K) stage(cur ^ 1, k0 + 32);

        const u16* as = As + cur * ASZ;
        const u16* bs = Bs + cur * BSZ;
        s16x8 af[TM], bf[NT];
#pragma unroll
        for (int x = 0; x < TM; ++x)
            af[x] = *(const s16x8*)&as[(wm * (TM * 16) + x * 16 + l16) * 32 + quad * 8];
#pragma unroll
        for (int y = 0; y < NT; ++y)
            bf[y] = *(const s16x8*)&bs[(wn * (NT * 16) + y * 16 + l16) * 32 + quad * 8];
#pragma unroll
        for (int x = 0; x < TM; ++x)
#pragma unroll
            for (int y = 0; y < NT; ++y)
                acc[x][y] = __builtin_amdgcn_mfma_f32_16x16x32_bf16(af[x], bf[y], acc[x][y], 0, 0, 0);
        cur ^= 1;
    }

    // ---- v-block epilogue (QKV fused, n0 >= 1024): LDS repack -> vT ----
    if (CMODE == 2 && n0 >= 1024) {
        u16* T = smem;                    // [BN][72] u16 = 36864 B, fits smem
        __syncthreads();                  // all waves done reading As/Bs
#pragma unroll
        for (int y = 0; y < NT; ++y) {
            const int crel = wn * (NT * 16) + y * 16 + l16;
            const float bval = g.bv[n0 - 1024 + crel];
#pragma unroll
            for (int x = 0; x < TM; ++x)
#pragma unroll
                for (int r = 0; r < 4; ++r) {
                    const int rrel = wm * (TM * 16) + x * 16 + quad * 4 + r;
                    T[crel * 72 + rrel] = f2bf(acc[x][y][r] + bval);
                }
        }
        __syncthreads();
        const int vb  = m0 >> 11;         // batch (BM=64 divides 2048)
        const int pos = m0 & 2047;
        u16* dst = g.vTd + (long)vb * (512l * 2048) + (long)(n0 - 1024) * 2048 + pos;
#pragma unroll
        for (int i = 0; i < BN / 32; ++i) {
            const int c  = i * 32 + (t >> 3);
            const int ms = (t & 7) * 8;
            *(u16x8*)(dst + (long)c * 2048 + ms) = *(const u16x8*)&T[c * 72 + ms];
        }
        return;
    }

    float rs[TM][4];
    if (CMODE == 3)
#pragma unroll
        for (int x = 0; x < TM; ++x)
#pragma unroll
            for (int r = 0; r < 4; ++r) rs[x][r] = 0.0f;

#pragma unroll
    for (int y = 0; y < NT; ++y) {
        const int col = n0 + wn * (NT * 16) + y * 16 + l16;
        float bval = 0.0f;
        if (CMODE == 2)
            bval = col < 512 ? g.bq[col] : g.bk[col - 512];
        else if (EPI >= 1)
            bval = g.bias[col];
#pragma unroll
        for (int x = 0; x < TM; ++x) {
#pragma unroll
            for (int r = 0; r < 4; ++r) {
                const int row = m0 + wm * (TM * 16) + x * 16 + quad * 4 + r;
                float v = acc[x][y][r] * g.scale + bval;
                if (EPI == 2) v = 0.5f * v * (1.0f + erff(v * 0.70710678118654752f));
                if (CMODE == 3) {
                    const float e = __expf(v);
                    rs[x][r] += e;
                    ((u16*)g.C + g.strC * batch)[(long)row * g.ldc + col] = f2bf(e);
                } else if (CMODE == 2) {
                    u16* dst = col < 512 ? g.qd : g.kd;
                    dst[(long)row * 512 + (col & 511)] = f2bf(v);
                } else if (SPLITK) {
                    float* dst = kh ? g.Cpart : (float*)g.C;
                    dst[g.strC * batch + (long)row * g.ldc + col] = v;
                } else if (CMODE == 1) {
                    ((float*)g.C + g.strC * batch)[(long)row * g.ldc + col] = v;
                } else {
                    ((u16*)g.C + g.strC * batch)[(long)row * g.ldc + col] = f2bf(v);
                }
            }
        }
    }

    if (CMODE == 3) {
#pragma unroll
        for (int x = 0; x < TM; ++x) {
#pragma unroll
            for (int r = 0; r < 4; ++r) {
                float s = rs[x][r];
                s += __shfl_xor(s, 1, 64);
                s += __shfl_xor(s, 2, 64);
                s += __shfl_xor(s, 4, 64);
                s += __shfl_xor(s, 8, 64);
                if (l16 == 0) {
                    const int row = m0 + wm * (TM * 16) + x * 16 + quad * 4 + r;
                    g.lsum[(long)(2 * blockIdx.x + wn) * 8192 + batch * 2048 + row] = s;
                }
            }
        }
    }
}

// out[i] = (out[i] + part[i]) / l[row].  4 f32 per thread, 4096 blocks.
__launch_bounds__(256)
__global__ void add_k(float* __restrict__ out, const float* __restrict__ part,
                      const float* __restrict__ lsum)
{
    const long i = ((long)blockIdx.x * 256 + threadIdx.x) * 4;
    const int row = (int)(i >> 9);                 // 512 f32 per row
    float l = 0.0f;
#pragma unroll
    for (int j = 0; j < 16; ++j) l += lsum[(long)j * 8192 + row];
    const float inv = 1.0f / l;
    f32x4 a = *(const f32x4*)(out + i);
    f32x4 b = *(const f32x4*)(part + i);
    a = (a + b) * inv;
    *(f32x4*)(out + i) = a;
}

extern "C" void kernel_launch(void* const* d_in, const int* in_sizes, int n_in,
                              void* d_out, int out_size, void* d_ws, size_t ws_size,
                              hipStream_t stream)
{
    const int*   tok = (const int*)d_in[0];
    const float* emb = (const float*)d_in[1];
    const float* W1  = (const float*)d_in[2];
    const float* b1  = (const float*)d_in[3];
    const float* Wq  = (const float*)d_in[4];
    const float* bq  = (const float*)d_in[5];
    const float* Wk  = (const float*)d_in[6];
    const float* bk  = (const float*)d_in[7];
    const float* Wv  = (const float*)d_in[8];
    const float* bv  = (const float*)d_in[9];
    float* out = (float*)d_out;

    u16* act   = (u16*)d_out;                  // [8192][512] bf16 (8 MiB)
    u16* wbase = act + 8192l * 512;
    u16* W1T = wbase;                          // [512][256]
    u16* WqT = wbase + 131072;                 // [1536][512] contiguous
    u16* WkT = WqT + 262144;
    u16* WvT = WkT + 262144;

    char* ws = (char*)d_ws;
    u16* q     = (u16*)(ws);
    u16* k     = (u16*)(ws + (8l  << 20));
    u16* vT    = (u16*)(ws + (16l << 20));     // [4][512][2048]
    u16* sc    = (u16*)(ws + (24l << 20));     // 32 MiB (e values)
    float* lsum = (float*)(ws + (56l << 20));  // [16][8192] f32
    u16* embB  = sc;                           // dead before sc written
    float* wsP = (float*)ws;                   // aliases q+k (dead by PV)

    const dim3 blk(256);
    const float iscl = 0.044194173824159216f;  // 1/sqrt(512)
    const long  TB = 2048l * 512;
    const long  SS = 2048l * 2048;

    // 0. prep: weight transposes (z<4) + XCD-striped gather+cvt (z>=4)
    PArgs p;
    p.wsrc[0] = W1; p.wsrc[1] = Wq; p.wsrc[2] = Wk; p.wsrc[3] = Wv;
    p.wdst[0] = W1T; p.wdst[1] = WqT; p.wdst[2] = WkT; p.wdst[3] = WvT;
    p.wK[0] = 256; p.wK[1] = 512; p.wK[2] = 512; p.wK[3] = 512;
    p.emb = emb; p.tok = tok; p.embB = embB;
    prep_k<<<dim3(8, 8, 20), blk, 0, stream>>>(p);

    // 1. act = gelu(embB @ W1T + b1)   M=8192 N=512 K=256  TM=2 BN=128 XSW
    {
        GArgs a = {};
        a.A = embB; a.B = W1T; a.bias = b1; a.C = act;
        a.K = 256; a.lda = 256; a.ldb = 256; a.ldc = 512; a.scale = 1.0f;
        gemm128<2, 4, 2, 0, false, false, true><<<dim3(4, 128, 1), blk, 0, stream>>>(a);
    }
    // 2. fused QKV   M=8192 N=1536 K=512  TM=2 BN=256 XSW (768 blocks)
    //    q,k row-major; v-blocks write vT directly via LDS repack.
    {
        GArgs a = {};
        a.A = act; a.B = WqT; a.K = 512; a.lda = 512; a.ldb = 512; a.scale = 1.0f;
        a.qd = q; a.kd = k; a.vTd = vT; a.bq = bq; a.bk = bk; a.bv = bv;
        gemm128<2, 8, 0, 2, false, false, true><<<dim3(6, 128, 1), blk, 0, stream>>>(a);
    }
    // 3. e = exp(q @ k^T / sqrt(512)) + row sums   M=N=2048 K=512  TM=4 BN=256
    {
        GArgs a = {};
        a.A = q; a.B = k; a.C = sc; a.lsum = lsum;
        a.K = 512; a.lda = 512; a.ldb = 512; a.ldc = 2048;
        a.strA = TB; a.strB = TB; a.strC = SS; a.scale = iscl;
        gemm128<4, 8, 0, 3, false, false, false><<<dim3(8, 16, 4), blk, 0, stream>>>(a);
    }
    // 4. raw = e @ vT^T   M=2048 N=512 K=2048  TM=2 BN=256, split-K x2, MX
    {
        GArgs a = {};
        a.A = sc; a.B = vT; a.C = out; a.Cpart = wsP;
        a.K = 2048; a.lda = 2048; a.ldb = 2048; a.ldc = 512;
        a.strA = SS; a.strB = TB; a.strC = TB; a.scale = 1.0f;
        gemm128<2, 8, 0, 1, true, true, false><<<dim3(32, 2, 8), blk, 0, stream>>>(a);
    }
    // 5. out = (kh0 + kh1) / l_row
    add_k<<<dim3(4096), blk, 0, stream>>>(out, wsP, lsum);
}